// Round 1
// baseline (1807.717 us; speedup 1.0000x reference)
//
#include <hip/hip_runtime.h>
#include <hip/hip_bf16.h>
#include <math.h>

#define NCOL 192   // 64 root | 64 rel0 | 64 rel1
#define BB   30    // bases

// ---------------- utility ----------------
__global__ void zero_f32(float* __restrict__ p, int n) {
  int i = blockIdx.x * blockDim.x + threadIdx.x;
  if (i < n) p[i] = 0.f;
}

// Wcat[k][j]: j<64 -> root[k][j]; else rel r=(j>>6)-1, o=j&63: sum_b comp[r,b]*basis[b,k,o]
__global__ void build_wcat(const float* __restrict__ basis, const float* __restrict__ comp,
                           const float* __restrict__ root, float* __restrict__ Wcat, int Kin) {
  int idx = blockIdx.x * blockDim.x + threadIdx.x;
  if (idx >= Kin * NCOL) return;
  int k = idx / NCOL, j = idx - k * NCOL;
  float v;
  if (j < 64) {
    v = root[k * 64 + j];
  } else {
    int r = (j >> 6) - 1, o = j & 63;
    float s = 0.f;
#pragma unroll
    for (int b = 0; b < BB; ++b)
      s = fmaf(comp[r * BB + b], basis[((size_t)b * Kin + k) * 64 + o], s);
    v = s;
  }
  Wcat[idx] = v;
}

// Y[N,192] = X[N,K] @ W[K,192].  192 threads (col each), BM rows staged in LDS.
template <int K, int BM>
__global__ __launch_bounds__(192) void gemm_xw(const float* __restrict__ X,
                                               const float* __restrict__ W,
                                               float* __restrict__ Y, int N) {
  extern __shared__ float xs[];  // BM * K floats
  const int KQ = K / 4;
  int row0 = blockIdx.x * BM;
  for (int idx = threadIdx.x; idx < BM * KQ; idx += 192) {
    int m = idx / KQ, kq = idx - m * KQ;
    int r = row0 + m;
    float4 v = make_float4(0.f, 0.f, 0.f, 0.f);
    if (r < N) v = ((const float4*)X)[(size_t)r * KQ + kq];
    ((float4*)xs)[idx] = v;
  }
  __syncthreads();
  int j = threadIdx.x;
  float acc[BM];
#pragma unroll
  for (int m = 0; m < BM; ++m) acc[m] = 0.f;
  for (int k = 0; k < K; k += 4) {
    float w0 = W[(k + 0) * NCOL + j];
    float w1 = W[(k + 1) * NCOL + j];
    float w2 = W[(k + 2) * NCOL + j];
    float w3 = W[(k + 3) * NCOL + j];
#pragma unroll
    for (int m = 0; m < BM; ++m) {
      float4 xv = *(const float4*)&xs[m * K + k];
      acc[m] = fmaf(xv.x, w0, acc[m]);
      acc[m] = fmaf(xv.y, w1, acc[m]);
      acc[m] = fmaf(xv.z, w2, acc[m]);
      acc[m] = fmaf(xv.w, w3, acc[m]);
    }
  }
#pragma unroll
  for (int m = 0; m < BM; ++m) {
    int r = row0 + m;
    if (r < N) Y[(size_t)r * NCOL + j] = acc[m];
  }
}

// per-(dst,etype) edge counts
__global__ void count_edges(const int* __restrict__ dst, const int* __restrict__ et,
                            float* __restrict__ cnt, int E) {
  int e = blockIdx.x * blockDim.x + threadIdx.x;
  if (e >= E) return;
  atomicAdd(&cnt[(size_t)dst[e] * 2 + et[e]], 1.0f);
}

__global__ void invert_cnt(float* __restrict__ cnt, int n) {
  int i = blockIdx.x * blockDim.x + threadIdx.x;
  if (i < n) cnt[i] = 1.0f / fmaxf(cnt[i], 1.0f);
}

// acc[n][j] = Y[n][j] (root part) + bias[j]
__global__ void init_acc(const float* __restrict__ Y, const float* __restrict__ bias,
                         float* __restrict__ acc, int N) {
  int idx = blockIdx.x * blockDim.x + threadIdx.x;
  if (idx >= N * 64) return;
  int n = idx >> 6, j = idx & 63;
  acc[idx] = Y[(size_t)n * NCOL + j] + bias[j];
}

// one wave per edge: acc[dst] += h_r[src] * inv_cnt[dst,r]
__global__ __launch_bounds__(256) void edge_agg(const int* __restrict__ src,
                                                const int* __restrict__ dst,
                                                const int* __restrict__ et,
                                                const float* __restrict__ Y,
                                                const float* __restrict__ inv,
                                                float* __restrict__ acc, int E) {
  int e = blockIdx.x * 4 + (threadIdx.x >> 6);
  if (e >= E) return;
  int lane = threadIdx.x & 63;
  int s = src[e], d = dst[e], r = et[e];
  float scale = inv[(size_t)d * 2 + r];
  float v = Y[(size_t)s * NCOL + 64 + (r << 6) + lane] * scale;
  atomicAdd(&acc[(size_t)d * 64 + lane], v);
}

__global__ void relu_inplace(float* __restrict__ p, int n) {
  int i = blockIdx.x * blockDim.x + threadIdx.x;
  if (i < n) p[i] = fmaxf(p[i], 0.f);
}

// ---------------- GAT ----------------
__device__ __forceinline__ float leaky(float x) { return x > 0.f ? x : 0.2f * x; }
__device__ __forceinline__ unsigned f2u(float f) {
  unsigned u = __float_as_uint(f);
  return (u & 0x80000000u) ? ~u : (u | 0x80000000u);
}
__device__ __forceinline__ float u2f(unsigned u) {
  return (u & 0x80000000u) ? __uint_as_float(u & 0x7fffffffu) : __uint_as_float(~u);
}

// hval[n] = dot(x2[n,:], w)  (wave per node)
__global__ __launch_bounds__(256) void gat_h(const float* __restrict__ x2,
                                             const float* __restrict__ w,
                                             float* __restrict__ hval, int N) {
  int n = blockIdx.x * 4 + (threadIdx.x >> 6);
  int lane = threadIdx.x & 63;
  if (n >= N) return;
  float v = x2[(size_t)n * 64 + lane] * w[lane];
#pragma unroll
  for (int o = 32; o > 0; o >>= 1) v += __shfl_down(v, o);
  if (lane == 0) hval[n] = v;
}

__global__ void gat_init_max(const float* __restrict__ hval, const float* __restrict__ as_,
                             const float* __restrict__ ad_, unsigned* __restrict__ emaxu, int N) {
  int n = blockIdx.x * blockDim.x + threadIdx.x;
  if (n >= N) return;
  float hv = hval[n];
  float es = leaky(hv * (*as_) + hv * (*ad_));  // self-loop score
  emaxu[n] = f2u(es);
}

__global__ void gat_edge_max(const int* __restrict__ src, const int* __restrict__ dst,
                             const float* __restrict__ hval, const float* __restrict__ as_,
                             const float* __restrict__ ad_, unsigned* __restrict__ emaxu, int E) {
  int e = blockIdx.x * blockDim.x + threadIdx.x;
  if (e >= E) return;
  float ev = leaky(hval[src[e]] * (*as_) + hval[dst[e]] * (*ad_));
  atomicMax(&emaxu[dst[e]], f2u(ev));
}

__global__ void gat_init_sum(const float* __restrict__ hval, const float* __restrict__ as_,
                             const float* __restrict__ ad_, const unsigned* __restrict__ emaxu,
                             float* __restrict__ denom, float* __restrict__ outacc, int N) {
  int n = blockIdx.x * blockDim.x + threadIdx.x;
  if (n >= N) return;
  float hv = hval[n];
  float es = leaky(hv * (*as_) + hv * (*ad_));
  float ex = expf(es - u2f(emaxu[n]));
  denom[n] = ex;
  outacc[n] = ex * hv;
}

__global__ void gat_edge_sum(const int* __restrict__ src, const int* __restrict__ dst,
                             const float* __restrict__ hval, const float* __restrict__ as_,
                             const float* __restrict__ ad_, const unsigned* __restrict__ emaxu,
                             float* __restrict__ denom, float* __restrict__ outacc, int E) {
  int e = blockIdx.x * blockDim.x + threadIdx.x;
  if (e >= E) return;
  int s = src[e], d = dst[e];
  float ev = leaky(hval[s] * (*as_) + hval[d] * (*ad_));
  float ex = expf(ev - u2f(emaxu[d]));
  atomicAdd(&denom[d], ex);
  atomicAdd(&outacc[d], ex * hval[s]);
}

__global__ void gat_final(const float* __restrict__ outacc, const float* __restrict__ denom,
                          const float* __restrict__ gb, float* __restrict__ out, int N) {
  int n = blockIdx.x * blockDim.x + threadIdx.x;
  if (n >= N) return;
  out[n] = outacc[n] / denom[n] + (*gb);
}

// ---------------- launch ----------------
extern "C" void kernel_launch(void* const* d_in, const int* in_sizes, int n_in,
                              void* d_out, int out_size, void* d_ws, size_t ws_size,
                              hipStream_t stream) {
  const float* x      = (const float*)d_in[0];
  const int*   eidx   = (const int*)d_in[1];
  const int*   etype  = (const int*)d_in[2];
  const float* basis1 = (const float*)d_in[3];
  const float* comp1  = (const float*)d_in[4];
  const float* root1  = (const float*)d_in[5];
  const float* bias1  = (const float*)d_in[6];
  const float* basis2 = (const float*)d_in[7];
  const float* comp2  = (const float*)d_in[8];
  const float* root2  = (const float*)d_in[9];
  const float* bias2  = (const float*)d_in[10];
  const float* gat_w  = (const float*)d_in[11];
  const float* att_s  = (const float*)d_in[12];
  const float* att_d  = (const float*)d_in[13];
  const float* gat_b  = (const float*)d_in[14];

  const int N = in_sizes[0] / 512;   // 100000
  const int E = in_sizes[1] / 2;     // 1600000
  const int* src = eidx;
  const int* dst = eidx + E;

  // workspace carve-up (bytes)
  char* ws = (char*)d_ws;
  float*    Y      = (float*)(ws);                               // N*192
  float*    acc1   = (float*)(ws + (size_t)N * NCOL * 4);        // N*64
  float*    acc2   = (float*)(ws + (size_t)N * (NCOL + 64) * 4); // N*64
  float*    cnt    = (float*)(ws + (size_t)N * (NCOL + 128) * 4);// N*2 (holds inverse after invert_cnt)
  char*     p      = ws + (size_t)N * (NCOL + 130) * 4;
  float*    Wcat   = (float*)p;                                  // 512*192
  p += 512 * NCOL * 4;
  float*    hval   = (float*)p; p += (size_t)N * 4;
  unsigned* emaxu  = (unsigned*)p; p += (size_t)N * 4;
  float*    denom  = (float*)p; p += (size_t)N * 4;
  float*    outacc = (float*)p;
  float*    out    = (float*)d_out;

  const int TB = 256;
  // counts (shared by both layers)
  zero_f32<<<(N * 2 + TB - 1) / TB, TB, 0, stream>>>(cnt, N * 2);
  count_edges<<<(E + TB - 1) / TB, TB, 0, stream>>>(dst, etype, cnt, E);
  invert_cnt<<<(N * 2 + TB - 1) / TB, TB, 0, stream>>>(cnt, N * 2);

  // ---- layer 1 (K=512) ----
  build_wcat<<<(512 * NCOL + TB - 1) / TB, TB, 0, stream>>>(basis1, comp1, root1, Wcat, 512);
  gemm_xw<512, 16><<<(N + 15) / 16, 192, 512 * 16 * 4, stream>>>(x, Wcat, Y, N);
  init_acc<<<(N * 64 + TB - 1) / TB, TB, 0, stream>>>(Y, bias1, acc1, N);
  edge_agg<<<(E + 3) / 4, TB, 0, stream>>>(src, dst, etype, Y, cnt, acc1, E);
  relu_inplace<<<(N * 64 + TB - 1) / TB, TB, 0, stream>>>(acc1, N * 64);

  // ---- layer 2 (K=64) ----
  build_wcat<<<(64 * NCOL + TB - 1) / TB, TB, 0, stream>>>(basis2, comp2, root2, Wcat, 64);
  gemm_xw<64, 16><<<(N + 15) / 16, 192, 64 * 16 * 4, stream>>>(acc1, Wcat, Y, N);
  init_acc<<<(N * 64 + TB - 1) / TB, TB, 0, stream>>>(Y, bias2, acc2, N);
  edge_agg<<<(E + 3) / 4, TB, 0, stream>>>(src, dst, etype, Y, cnt, acc2, E);

  // ---- GAT ----
  gat_h<<<(N + 3) / 4, TB, 0, stream>>>(acc2, gat_w, hval, N);
  gat_init_max<<<(N + TB - 1) / TB, TB, 0, stream>>>(hval, att_s, att_d, emaxu, N);
  gat_edge_max<<<(E + TB - 1) / TB, TB, 0, stream>>>(src, dst, hval, att_s, att_d, emaxu, E);
  gat_init_sum<<<(N + TB - 1) / TB, TB, 0, stream>>>(hval, att_s, att_d, emaxu, denom, outacc, N);
  gat_edge_sum<<<(E + TB - 1) / TB, TB, 0, stream>>>(src, dst, hval, att_s, att_d, emaxu,
                                                     denom, outacc, E);
  gat_final<<<(N + TB - 1) / TB, TB, 0, stream>>>(outacc, denom, gat_b, out, N);
}

// Round 2
// 1229.789 us; speedup vs baseline: 1.4699x; 1.4699x over previous
//
#include <hip/hip_runtime.h>
#include <hip/hip_bf16.h>
#include <math.h>

#define NCOL 192   // 64 root | 64 rel0 | 64 rel1
#define BB   30    // bases

typedef short bf16x8 __attribute__((ext_vector_type(8)));
typedef float f32x4  __attribute__((ext_vector_type(4)));

__device__ __forceinline__ ushort f2bf(float f) {
  unsigned u = __float_as_uint(f);
  unsigned r = u + 0x7fff + ((u >> 16) & 1);   // RTNE
  return (ushort)(r >> 16);
}

// ---------------- utility ----------------
__global__ void zero_f32(float* __restrict__ p, int n) {
  int i = blockIdx.x * blockDim.x + threadIdx.x;
  if (i < n) p[i] = 0.f;
}

// Packed bf16 W: Wpk[(k>>3)*192 + j][k&7]  (each B-fragment = 16B contiguous)
// j<64 -> root[k][j]; else rel r=(j>>6)-1, o=j&63: sum_b comp[r,b]*basis[b,k,o]
__global__ void build_wpk(const float* __restrict__ basis, const float* __restrict__ comp,
                          const float* __restrict__ root, ushort* __restrict__ Wpk, int Kin) {
  int idx = blockIdx.x * blockDim.x + threadIdx.x;
  if (idx >= Kin * NCOL) return;
  int k = idx / NCOL, j = idx - k * NCOL;
  float v;
  if (j < 64) {
    v = root[k * 64 + j];
  } else {
    int r = (j >> 6) - 1, o = j & 63;
    float s = 0.f;
#pragma unroll
    for (int b = 0; b < BB; ++b)
      s = fmaf(comp[r * BB + b], basis[((size_t)b * Kin + k) * 64 + o], s);
    v = s;
  }
  Wpk[(((size_t)(k >> 3) * NCOL + j) << 3) + (k & 7)] = f2bf(v);
}

// Y[N,192] = X[N,K](f32) @ Wpk(bf16 packed), MFMA 16x16x32 bf16, f32 accum.
// Block: 64 rows x 192 cols; 4 waves x (16 rows x 192 cols). Full K staged in LDS.
template <int K>
__global__ __launch_bounds__(256) void gemm_mfma(const float* __restrict__ X,
                                                 const ushort* __restrict__ Wpk,
                                                 float* __restrict__ Y, int N) {
  __shared__ ushort As[64 * K];  // bf16, XOR-swizzled rows
  const int row0 = blockIdx.x * 64;

  // stage: f32 -> bf16, coalesced float4 reads, swizzled 8B LDS writes
  constexpr int KQ = K / 4;
  for (int idx = threadIdx.x; idx < 64 * KQ; idx += 256) {
    int row = idx / KQ, kq = idx - row * KQ;
    int r = row0 + row;
    float4 v = make_float4(0.f, 0.f, 0.f, 0.f);
    if (r < N) v = ((const float4*)X)[(size_t)r * KQ + kq];
    ushort4 b;
    b.x = f2bf(v.x); b.y = f2bf(v.y); b.z = f2bf(v.z); b.w = f2bf(v.w);
    int byte = (row * K + kq * 4) * 2;
    byte ^= (row & 7) << 4;
    *(ushort4*)((char*)As + byte) = b;
  }
  __syncthreads();

  const int wid  = threadIdx.x >> 6;
  const int lane = threadIdx.x & 63;
  const int lrow = lane & 15;      // frag row (A) / col (B,C)
  const int lhi  = lane >> 4;      // k-group / C row-group

  f32x4 acc[12];
#pragma unroll
  for (int c = 0; c < 12; ++c) acc[c] = (f32x4){0.f, 0.f, 0.f, 0.f};

  const int arow = wid * 16 + lrow;
#pragma unroll
  for (int t = 0; t < K / 32; ++t) {
    int abyte = (arow * K + t * 32 + lhi * 8) * 2;
    abyte ^= (arow & 7) << 4;
    bf16x8 a = *(const bf16x8*)((const char*)As + abyte);
    const bf16x8* bp = (const bf16x8*)Wpk + (size_t)(t * 4 + lhi) * NCOL + lrow;
#pragma unroll
    for (int c = 0; c < 12; ++c) {
      bf16x8 b = bp[c * 16];
      acc[c] = __builtin_amdgcn_mfma_f32_16x16x32_bf16(a, b, acc[c], 0, 0, 0);
    }
  }

  // C/D: col = lane&15, row = (lane>>4)*4 + reg   [m89]
#pragma unroll
  for (int c = 0; c < 12; ++c) {
#pragma unroll
    for (int j = 0; j < 4; ++j) {
      int r = row0 + wid * 16 + lhi * 4 + j;
      if (r < N) Y[(size_t)r * NCOL + c * 16 + lrow] = acc[c][j];
    }
  }
}

// per-(dst,etype) edge counts
__global__ void count_edges(const int* __restrict__ dst, const int* __restrict__ et,
                            float* __restrict__ cnt, int E) {
  int e = blockIdx.x * blockDim.x + threadIdx.x;
  if (e >= E) return;
  atomicAdd(&cnt[(size_t)dst[e] * 2 + et[e]], 1.0f);
}

__global__ void invert_cnt(float* __restrict__ cnt, int n) {
  int i = blockIdx.x * blockDim.x + threadIdx.x;
  if (i < n) cnt[i] = 1.0f / fmaxf(cnt[i], 1.0f);
}

// acc[n][j] = Y[n][j] (root part) + bias[j]
__global__ void init_acc(const float* __restrict__ Y, const float* __restrict__ bias,
                         float* __restrict__ acc, int N) {
  int idx = blockIdx.x * blockDim.x + threadIdx.x;
  if (idx >= N * 64) return;
  int n = idx >> 6, j = idx & 63;
  acc[idx] = Y[(size_t)n * NCOL + j] + bias[j];
}

// one wave per edge: acc[dst] += h_r[src] * inv_cnt[dst,r]
__global__ __launch_bounds__(256) void edge_agg(const int* __restrict__ src,
                                                const int* __restrict__ dst,
                                                const int* __restrict__ et,
                                                const float* __restrict__ Y,
                                                const float* __restrict__ inv,
                                                float* __restrict__ acc, int E) {
  int e = blockIdx.x * 4 + (threadIdx.x >> 6);
  if (e >= E) return;
  int lane = threadIdx.x & 63;
  int s = src[e], d = dst[e], r = et[e];
  float scale = inv[(size_t)d * 2 + r];
  float v = Y[(size_t)s * NCOL + 64 + (r << 6) + lane] * scale;
  atomicAdd(&acc[(size_t)d * 64 + lane], v);
}

__global__ void relu_inplace(float* __restrict__ p, int n) {
  int i = blockIdx.x * blockDim.x + threadIdx.x;
  if (i < n) p[i] = fmaxf(p[i], 0.f);
}

// ---------------- GAT ----------------
__device__ __forceinline__ float leaky(float x) { return x > 0.f ? x : 0.2f * x; }
__device__ __forceinline__ unsigned f2u(float f) {
  unsigned u = __float_as_uint(f);
  return (u & 0x80000000u) ? ~u : (u | 0x80000000u);
}
__device__ __forceinline__ float u2f(unsigned u) {
  return (u & 0x80000000u) ? __uint_as_float(u & 0x7fffffffu) : __uint_as_float(~u);
}

// hval[n] = dot(x2[n,:], w)  (wave per node)
__global__ __launch_bounds__(256) void gat_h(const float* __restrict__ x2,
                                             const float* __restrict__ w,
                                             float* __restrict__ hval, int N) {
  int n = blockIdx.x * 4 + (threadIdx.x >> 6);
  int lane = threadIdx.x & 63;
  if (n >= N) return;
  float v = x2[(size_t)n * 64 + lane] * w[lane];
#pragma unroll
  for (int o = 32; o > 0; o >>= 1) v += __shfl_down(v, o);
  if (lane == 0) hval[n] = v;
}

__global__ void gat_init_max(const float* __restrict__ hval, const float* __restrict__ as_,
                             const float* __restrict__ ad_, unsigned* __restrict__ emaxu, int N) {
  int n = blockIdx.x * blockDim.x + threadIdx.x;
  if (n >= N) return;
  float hv = hval[n];
  float es = leaky(hv * (*as_) + hv * (*ad_));  // self-loop score
  emaxu[n] = f2u(es);
}

__global__ void gat_edge_max(const int* __restrict__ src, const int* __restrict__ dst,
                             const float* __restrict__ hval, const float* __restrict__ as_,
                             const float* __restrict__ ad_, unsigned* __restrict__ emaxu, int E) {
  int e = blockIdx.x * blockDim.x + threadIdx.x;
  if (e >= E) return;
  float ev = leaky(hval[src[e]] * (*as_) + hval[dst[e]] * (*ad_));
  atomicMax(&emaxu[dst[e]], f2u(ev));
}

__global__ void gat_init_sum(const float* __restrict__ hval, const float* __restrict__ as_,
                             const float* __restrict__ ad_, const unsigned* __restrict__ emaxu,
                             float* __restrict__ denom, float* __restrict__ outacc, int N) {
  int n = blockIdx.x * blockDim.x + threadIdx.x;
  if (n >= N) return;
  float hv = hval[n];
  float es = leaky(hv * (*as_) + hv * (*ad_));
  float ex = expf(es - u2f(emaxu[n]));
  denom[n] = ex;
  outacc[n] = ex * hv;
}

__global__ void gat_edge_sum(const int* __restrict__ src, const int* __restrict__ dst,
                             const float* __restrict__ hval, const float* __restrict__ as_,
                             const float* __restrict__ ad_, const unsigned* __restrict__ emaxu,
                             float* __restrict__ denom, float* __restrict__ outacc, int E) {
  int e = blockIdx.x * blockDim.x + threadIdx.x;
  if (e >= E) return;
  int s = src[e], d = dst[e];
  float ev = leaky(hval[s] * (*as_) + hval[d] * (*ad_));
  float ex = expf(ev - u2f(emaxu[d]));
  atomicAdd(&denom[d], ex);
  atomicAdd(&outacc[d], ex * hval[s]);
}

__global__ void gat_final(const float* __restrict__ outacc, const float* __restrict__ denom,
                          const float* __restrict__ gb, float* __restrict__ out, int N) {
  int n = blockIdx.x * blockDim.x + threadIdx.x;
  if (n >= N) return;
  out[n] = outacc[n] / denom[n] + (*gb);
}

// ---------------- launch ----------------
extern "C" void kernel_launch(void* const* d_in, const int* in_sizes, int n_in,
                              void* d_out, int out_size, void* d_ws, size_t ws_size,
                              hipStream_t stream) {
  const float* x      = (const float*)d_in[0];
  const int*   eidx   = (const int*)d_in[1];
  const int*   etype  = (const int*)d_in[2];
  const float* basis1 = (const float*)d_in[3];
  const float* comp1  = (const float*)d_in[4];
  const float* root1  = (const float*)d_in[5];
  const float* bias1  = (const float*)d_in[6];
  const float* basis2 = (const float*)d_in[7];
  const float* comp2  = (const float*)d_in[8];
  const float* root2  = (const float*)d_in[9];
  const float* bias2  = (const float*)d_in[10];
  const float* gat_w  = (const float*)d_in[11];
  const float* att_s  = (const float*)d_in[12];
  const float* att_d  = (const float*)d_in[13];
  const float* gat_b  = (const float*)d_in[14];

  const int N = in_sizes[0] / 512;   // 100000
  const int E = in_sizes[1] / 2;     // 1600000
  const int* src = eidx;
  const int* dst = eidx + E;

  // workspace carve-up (bytes)
  char* ws = (char*)d_ws;
  float*    Y      = (float*)(ws);                               // N*192
  float*    acc1   = (float*)(ws + (size_t)N * NCOL * 4);        // N*64
  float*    acc2   = (float*)(ws + (size_t)N * (NCOL + 64) * 4); // N*64
  float*    cnt    = (float*)(ws + (size_t)N * (NCOL + 128) * 4);// N*2 (holds inverse)
  char*     p      = ws + (size_t)N * (NCOL + 130) * 4;
  ushort*   Wpk    = (ushort*)p;                                 // K/8 x 192 x 8 bf16 (max 512*192)
  p += 512 * NCOL * 4;
  float*    hval   = (float*)p; p += (size_t)N * 4;
  unsigned* emaxu  = (unsigned*)p; p += (size_t)N * 4;
  float*    denom  = (float*)p; p += (size_t)N * 4;
  float*    outacc = (float*)p;
  float*    out    = (float*)d_out;

  const int TB = 256;
  const int GB = (N + 63) / 64;  // gemm blocks

  // counts (shared by both layers)
  zero_f32<<<(N * 2 + TB - 1) / TB, TB, 0, stream>>>(cnt, N * 2);
  count_edges<<<(E + TB - 1) / TB, TB, 0, stream>>>(dst, etype, cnt, E);
  invert_cnt<<<(N * 2 + TB - 1) / TB, TB, 0, stream>>>(cnt, N * 2);

  // ---- layer 1 (K=512) ----
  build_wpk<<<(512 * NCOL + TB - 1) / TB, TB, 0, stream>>>(basis1, comp1, root1, Wpk, 512);
  gemm_mfma<512><<<GB, 256, 0, stream>>>(x, Wpk, Y, N);
  init_acc<<<(N * 64 + TB - 1) / TB, TB, 0, stream>>>(Y, bias1, acc1, N);
  edge_agg<<<(E + 3) / 4, TB, 0, stream>>>(src, dst, etype, Y, cnt, acc1, E);
  relu_inplace<<<(N * 64 + TB - 1) / TB, TB, 0, stream>>>(acc1, N * 64);

  // ---- layer 2 (K=64) ----
  build_wpk<<<(64 * NCOL + TB - 1) / TB, TB, 0, stream>>>(basis2, comp2, root2, Wpk, 64);
  gemm_mfma<64><<<GB, 256, 0, stream>>>(acc1, Wpk, Y, N);
  init_acc<<<(N * 64 + TB - 1) / TB, TB, 0, stream>>>(Y, bias2, acc2, N);
  edge_agg<<<(E + 3) / 4, TB, 0, stream>>>(src, dst, etype, Y, cnt, acc2, E);

  // ---- GAT (f32 throughout) ----
  gat_h<<<(N + 3) / 4, TB, 0, stream>>>(acc2, gat_w, hval, N);
  gat_init_max<<<(N + TB - 1) / TB, TB, 0, stream>>>(hval, att_s, att_d, emaxu, N);
  gat_edge_max<<<(E + TB - 1) / TB, TB, 0, stream>>>(src, dst, hval, att_s, att_d, emaxu, E);
  gat_init_sum<<<(N + TB - 1) / TB, TB, 0, stream>>>(hval, att_s, att_d, emaxu, denom, outacc, N);
  gat_edge_sum<<<(E + TB - 1) / TB, TB, 0, stream>>>(src, dst, hval, att_s, att_d, emaxu,
                                                     denom, outacc, E);
  gat_final<<<(N + TB - 1) / TB, TB, 0, stream>>>(outacc, denom, gat_b, out, N);
}

// Round 3
// 572.111 us; speedup vs baseline: 3.1597x; 2.1496x over previous
//
#include <hip/hip_runtime.h>
#include <hip/hip_bf16.h>
#include <math.h>

#define NCOL 192   // 64 root | 64 rel0 | 64 rel1
#define BB   30    // bases
#define SCAN_T 256
#define SCAN_ELEMS 1024   // per scan block (4 per thread)

typedef short bf16x8 __attribute__((ext_vector_type(8)));
typedef float f32x4  __attribute__((ext_vector_type(4)));

__device__ __forceinline__ ushort f2bf(float f) {
  unsigned u = __float_as_uint(f);
  unsigned r = u + 0x7fff + ((u >> 16) & 1);   // RTNE
  return (ushort)(r >> 16);
}

// ---------------- CSR build ----------------
__global__ void zero_int(int* __restrict__ p, int n) {
  int i = blockIdx.x * blockDim.x + threadIdx.x;
  if (i < n) p[i] = 0;
}

__global__ void hist_deg(const int* __restrict__ dst, int* __restrict__ deg, int E) {
  int e = blockIdx.x * blockDim.x + threadIdx.x;
  if (e >= E) return;
  atomicAdd(&deg[dst[e]], 1);
}

// per-block exclusive scan of deg -> rowptr[0..N), block totals -> partial[b]
__global__ __launch_bounds__(SCAN_T) void scan_local(const int* __restrict__ deg,
                                                     int* __restrict__ rowptr,
                                                     int* __restrict__ partial, int N) {
  __shared__ int sdata[SCAN_T];
  int t = threadIdx.x;
  int base = blockIdx.x * SCAN_ELEMS + t * 4;
  int v[4], s = 0;
#pragma unroll
  for (int k = 0; k < 4; ++k) {
    v[k] = (base + k < N) ? deg[base + k] : 0;
    s += v[k];
  }
  sdata[t] = s;
  __syncthreads();
  for (int off = 1; off < SCAN_T; off <<= 1) {
    int add = (t >= off) ? sdata[t - off] : 0;
    __syncthreads();
    sdata[t] += add;
    __syncthreads();
  }
  int run = sdata[t] - s;  // exclusive prefix of this thread's chunk
  if (t == SCAN_T - 1) partial[blockIdx.x] = sdata[t];
#pragma unroll
  for (int k = 0; k < 4; ++k) {
    if (base + k < N) rowptr[base + k] = run;
    run += v[k];
  }
}

// single-block exclusive scan of partial[0..nb), total appended at partial[nb]
__global__ __launch_bounds__(SCAN_T) void scan_partial(int* __restrict__ partial, int nb) {
  __shared__ int sdata[SCAN_T];
  int t = threadIdx.x;
  int v = (t < nb) ? partial[t] : 0;
  sdata[t] = v;
  __syncthreads();
  for (int off = 1; off < SCAN_T; off <<= 1) {
    int add = (t >= off) ? sdata[t - off] : 0;
    __syncthreads();
    sdata[t] += add;
    __syncthreads();
  }
  if (t < nb) partial[t] = sdata[t] - v;
  if (t == nb - 1) partial[nb] = sdata[t];
}

// rowptr[i] += partial[block]; rowptr[N] = total; zero fill for scatter
__global__ void scan_add(int* __restrict__ rowptr, const int* __restrict__ partial,
                         int* __restrict__ fill, int N) {
  int i = blockIdx.x * blockDim.x + threadIdx.x;
  if (i < N) {
    rowptr[i] += partial[i / SCAN_ELEMS];
    fill[i] = 0;
  }
  if (i == N) rowptr[N] = partial[(N + SCAN_ELEMS - 1) / SCAN_ELEMS];
}

__global__ void scatter_edges(const int* __restrict__ src, const int* __restrict__ dst,
                              const int* __restrict__ et, const int* __restrict__ rowptr,
                              int* __restrict__ fill, int* __restrict__ srcpk, int E) {
  int e = blockIdx.x * blockDim.x + threadIdx.x;
  if (e >= E) return;
  int d = dst[e];
  int pos = rowptr[d] + atomicAdd(&fill[d], 1);
  srcpk[pos] = src[e] | (et[e] << 30);
}

// ---------------- weights ----------------
// Packed bf16 W: Wpk[(k>>3)*192 + j][k&7]
__global__ void build_wpk(const float* __restrict__ basis, const float* __restrict__ comp,
                          const float* __restrict__ root, ushort* __restrict__ Wpk, int Kin) {
  int idx = blockIdx.x * blockDim.x + threadIdx.x;
  if (idx >= Kin * NCOL) return;
  int k = idx / NCOL, j = idx - k * NCOL;
  float v;
  if (j < 64) {
    v = root[k * 64 + j];
  } else {
    int r = (j >> 6) - 1, o = j & 63;
    float s = 0.f;
#pragma unroll
    for (int b = 0; b < BB; ++b)
      s = fmaf(comp[r * BB + b], basis[((size_t)b * Kin + k) * 64 + o], s);
    v = s;
  }
  Wpk[(((size_t)(k >> 3) * NCOL + j) << 3) + (k & 7)] = f2bf(v);
}

// ---------------- GEMM (MFMA bf16) ----------------
template <int K>
__global__ __launch_bounds__(256) void gemm_mfma(const float* __restrict__ X,
                                                 const ushort* __restrict__ Wpk,
                                                 float* __restrict__ Y, int N) {
  __shared__ ushort As[64 * K];  // bf16, XOR-swizzled rows
  const int row0 = blockIdx.x * 64;
  constexpr int KQ = K / 4;
  for (int idx = threadIdx.x; idx < 64 * KQ; idx += 256) {
    int row = idx / KQ, kq = idx - row * KQ;
    int r = row0 + row;
    float4 v = make_float4(0.f, 0.f, 0.f, 0.f);
    if (r < N) v = ((const float4*)X)[(size_t)r * KQ + kq];
    ushort4 b;
    b.x = f2bf(v.x); b.y = f2bf(v.y); b.z = f2bf(v.z); b.w = f2bf(v.w);
    int byte = (row * K + kq * 4) * 2;
    byte ^= (row & 7) << 4;
    *(ushort4*)((char*)As + byte) = b;
  }
  __syncthreads();

  const int wid  = threadIdx.x >> 6;
  const int lane = threadIdx.x & 63;
  const int lrow = lane & 15;
  const int lhi  = lane >> 4;

  f32x4 acc[12];
#pragma unroll
  for (int c = 0; c < 12; ++c) acc[c] = (f32x4){0.f, 0.f, 0.f, 0.f};

  const int arow = wid * 16 + lrow;
#pragma unroll
  for (int t = 0; t < K / 32; ++t) {
    int abyte = (arow * K + t * 32 + lhi * 8) * 2;
    abyte ^= (arow & 7) << 4;
    bf16x8 a = *(const bf16x8*)((const char*)As + abyte);
    const bf16x8* bp = (const bf16x8*)Wpk + (size_t)(t * 4 + lhi) * NCOL + lrow;
#pragma unroll
    for (int c = 0; c < 12; ++c) {
      bf16x8 b = bp[c * 16];
      acc[c] = __builtin_amdgcn_mfma_f32_16x16x32_bf16(a, b, acc[c], 0, 0, 0);
    }
  }

  // C/D: col = lane&15, row = (lane>>4)*4 + reg   [m89]
#pragma unroll
  for (int c = 0; c < 12; ++c) {
#pragma unroll
    for (int j = 0; j < 4; ++j) {
      int r = row0 + wid * 16 + lhi * 4 + j;
      if (r < N) Y[(size_t)r * NCOL + c * 16 + lrow] = acc[c][j];
    }
  }
}

// ---------------- fused per-node aggregation ----------------
// wave per node, lane per feature. res = root + bias + mean_r0 + mean_r1 (+relu)
// GATH: also hval[n] = dot(res, gw) via shuffle reduce (acc2 never materialized)
template <int RELU, int GATH>
__global__ __launch_bounds__(256) void fused_agg(const float* __restrict__ Y,
                                                 const int* __restrict__ rowptr,
                                                 const int* __restrict__ srcpk,
                                                 const float* __restrict__ bias,
                                                 const float* __restrict__ gw,
                                                 float* __restrict__ accout,
                                                 float* __restrict__ hval, int N) {
  int n = blockIdx.x * 4 + (threadIdx.x >> 6);
  if (n >= N) return;
  int lane = threadIdx.x & 63;
  float a0 = 0.f, a1 = 0.f;
  int c0 = 0, c1 = 0;
  int beg = rowptr[n], end = rowptr[n + 1];
  int i = beg;
  for (; i + 1 < end; i += 2) {
    int pk0 = srcpk[i], pk1 = srcpk[i + 1];
    int s0 = pk0 & 0x3fffffff, r0 = pk0 >> 30;
    int s1 = pk1 & 0x3fffffff, r1 = pk1 >> 30;
    float v0 = Y[(size_t)s0 * NCOL + 64 + (r0 << 6) + lane];
    float v1 = Y[(size_t)s1 * NCOL + 64 + (r1 << 6) + lane];
    if (r0) { a1 += v0; c1++; } else { a0 += v0; c0++; }
    if (r1) { a1 += v1; c1++; } else { a0 += v1; c0++; }
  }
  if (i < end) {
    int pk = srcpk[i];
    int s = pk & 0x3fffffff, r = pk >> 30;
    float v = Y[(size_t)s * NCOL + 64 + (r << 6) + lane];
    if (r) { a1 += v; c1++; } else { a0 += v; c0++; }
  }
  float res = Y[(size_t)n * NCOL + lane] + bias[lane]
            + a0 / (float)(c0 > 1 ? c0 : 1) + a1 / (float)(c1 > 1 ? c1 : 1);
  if (RELU) res = fmaxf(res, 0.f);
  if (accout) accout[(size_t)n * 64 + lane] = res;
  if (GATH) {
    float v = res * gw[lane];
#pragma unroll
    for (int o = 32; o > 0; o >>= 1) v += __shfl_down(v, o);
    if (lane == 0) hval[n] = v;
  }
}

// ---------------- GAT (CSR, thread per node) ----------------
__device__ __forceinline__ float leaky(float x) { return x > 0.f ? x : 0.2f * x; }

__global__ __launch_bounds__(256) void gat_csr(const int* __restrict__ rowptr,
                                               const int* __restrict__ srcpk,
                                               const float* __restrict__ hval,
                                               const float* __restrict__ as_,
                                               const float* __restrict__ ad_,
                                               const float* __restrict__ gb,
                                               float* __restrict__ out, int N) {
  int n = blockIdx.x * blockDim.x + threadIdx.x;
  if (n >= N) return;
  float as = *as_, ad = *ad_;
  float hv = hval[n];
  float adn = hv * ad;
  float eself = leaky(hv * as + adn);
  float m = eself;
  int beg = rowptr[n], end = rowptr[n + 1];
  for (int i = beg; i < end; ++i) {
    int s = srcpk[i] & 0x3fffffff;
    float e = leaky(hval[s] * as + adn);
    m = fmaxf(m, e);
  }
  float den = expf(eself - m);
  float acc = den * hv;
  for (int i = beg; i < end; ++i) {
    int s = srcpk[i] & 0x3fffffff;
    float hs = hval[s];
    float e = leaky(hs * as + adn);
    float ex = expf(e - m);
    den += ex;
    acc += ex * hs;
  }
  out[n] = acc / den + *gb;
}

// ---------------- launch ----------------
extern "C" void kernel_launch(void* const* d_in, const int* in_sizes, int n_in,
                              void* d_out, int out_size, void* d_ws, size_t ws_size,
                              hipStream_t stream) {
  const float* x      = (const float*)d_in[0];
  const int*   eidx   = (const int*)d_in[1];
  const int*   etype  = (const int*)d_in[2];
  const float* basis1 = (const float*)d_in[3];
  const float* comp1  = (const float*)d_in[4];
  const float* root1  = (const float*)d_in[5];
  const float* bias1  = (const float*)d_in[6];
  const float* basis2 = (const float*)d_in[7];
  const float* comp2  = (const float*)d_in[8];
  const float* root2  = (const float*)d_in[9];
  const float* bias2  = (const float*)d_in[10];
  const float* gat_w  = (const float*)d_in[11];
  const float* att_s  = (const float*)d_in[12];
  const float* att_d  = (const float*)d_in[13];
  const float* gat_b  = (const float*)d_in[14];

  const int N = in_sizes[0] / 512;   // 100000
  const int E = in_sizes[1] / 2;     // 1600000
  const int* src = eidx;
  const int* dst = eidx + E;

  // workspace carve-up (16B-aligned segments)
  char* p = (char*)d_ws;
  float* Y    = (float*)p; p += (size_t)N * NCOL * 4;          // 76.8 MB
  float* acc1 = (float*)p; p += (size_t)N * 64 * 4;            // 25.6 MB
  ushort* Wpk = (ushort*)p; p += (size_t)512 * NCOL * 2;       // 0.2 MB
  float* hval = (float*)p; p += (size_t)N * 4;
  int* deg    = (int*)p;   p += (size_t)N * 4;                 // reused as fill
  int* rowptr = (int*)p;   p += (size_t)(N + 16) * 4;
  int* partial= (int*)p;   p += (size_t)(SCAN_T + 16) * 4;
  int* srcpk  = (int*)p;   p += (size_t)E * 4;                 // 6.4 MB
  float* out  = (float*)d_out;
  int* fill   = deg;

  const int TB = 256;
  const int GB = (N + 63) / 64;
  const int nb = (N + SCAN_ELEMS - 1) / SCAN_ELEMS;

  // ---- CSR build (shared by both layers and GAT) ----
  zero_int<<<(N + TB - 1) / TB, TB, 0, stream>>>(deg, N);
  hist_deg<<<(E + TB - 1) / TB, TB, 0, stream>>>(dst, deg, E);
  scan_local<<<nb, SCAN_T, 0, stream>>>(deg, rowptr, partial, N);
  scan_partial<<<1, SCAN_T, 0, stream>>>(partial, nb);
  scan_add<<<(N + 1 + TB - 1) / TB, TB, 0, stream>>>(rowptr, partial, fill, N);
  scatter_edges<<<(E + TB - 1) / TB, TB, 0, stream>>>(src, dst, etype, rowptr, fill, srcpk, E);

  // ---- layer 1 (K=512) ----
  build_wpk<<<(512 * NCOL + TB - 1) / TB, TB, 0, stream>>>(basis1, comp1, root1, Wpk, 512);
  gemm_mfma<512><<<GB, 256, 0, stream>>>(x, Wpk, Y, N);
  fused_agg<1, 0><<<(N + 3) / 4, TB, 0, stream>>>(Y, rowptr, srcpk, bias1, nullptr, acc1,
                                                  nullptr, N);

  // ---- layer 2 (K=64) ----
  build_wpk<<<(64 * NCOL + TB - 1) / TB, TB, 0, stream>>>(basis2, comp2, root2, Wpk, 64);
  gemm_mfma<64><<<GB, 256, 0, stream>>>(acc1, Wpk, Y, N);
  fused_agg<0, 1><<<(N + 3) / 4, TB, 0, stream>>>(Y, rowptr, srcpk, bias2, gat_w, nullptr,
                                                  hval, N);

  // ---- GAT ----
  gat_csr<<<(N + TB - 1) / TB, TB, 0, stream>>>(rowptr, srcpk, hval, att_s, att_d, gat_b,
                                                out, N);
}

// Round 4
// 501.034 us; speedup vs baseline: 3.6080x; 1.1419x over previous
//
#include <hip/hip_runtime.h>
#include <hip/hip_bf16.h>
#include <math.h>

#define NCOL 192   // 64 root | 64 rel0 | 64 rel1
#define BB   30    // bases
#define SCAN_T 256
#define SCAN_ELEMS 1024   // per scan block (4 per thread)

typedef short bf16x8 __attribute__((ext_vector_type(8)));
typedef float f32x4  __attribute__((ext_vector_type(4)));

__device__ __forceinline__ ushort f2bf(float f) {
  unsigned u = __float_as_uint(f);
  unsigned r = u + 0x7fff + ((u >> 16) & 1);   // RTNE
  return (ushort)(r >> 16);
}

// ---------------- CSR build ----------------
__global__ void zero_int(int* __restrict__ p, int n) {
  int i = blockIdx.x * blockDim.x + threadIdx.x;
  if (i < n) p[i] = 0;
}

__global__ void hist_deg(const int* __restrict__ dst, int* __restrict__ deg, int E) {
  int e = blockIdx.x * blockDim.x + threadIdx.x;
  if (e >= E) return;
  atomicAdd(&deg[dst[e]], 1);
}

// per-block exclusive scan of deg -> rowptr[0..N), block totals -> partial[b]
__global__ __launch_bounds__(SCAN_T) void scan_local(const int* __restrict__ deg,
                                                     int* __restrict__ rowptr,
                                                     int* __restrict__ partial, int N) {
  __shared__ int sdata[SCAN_T];
  int t = threadIdx.x;
  int base = blockIdx.x * SCAN_ELEMS + t * 4;
  int v[4], s = 0;
#pragma unroll
  for (int k = 0; k < 4; ++k) {
    v[k] = (base + k < N) ? deg[base + k] : 0;
    s += v[k];
  }
  sdata[t] = s;
  __syncthreads();
  for (int off = 1; off < SCAN_T; off <<= 1) {
    int add = (t >= off) ? sdata[t - off] : 0;
    __syncthreads();
    sdata[t] += add;
    __syncthreads();
  }
  int run = sdata[t] - s;  // exclusive prefix of this thread's chunk
  if (t == SCAN_T - 1) partial[blockIdx.x] = sdata[t];
#pragma unroll
  for (int k = 0; k < 4; ++k) {
    if (base + k < N) rowptr[base + k] = run;
    run += v[k];
  }
}

// single-block exclusive scan of partial[0..nb), total appended at partial[nb]
__global__ __launch_bounds__(SCAN_T) void scan_partial(int* __restrict__ partial, int nb) {
  __shared__ int sdata[SCAN_T];
  int t = threadIdx.x;
  int v = (t < nb) ? partial[t] : 0;
  sdata[t] = v;
  __syncthreads();
  for (int off = 1; off < SCAN_T; off <<= 1) {
    int add = (t >= off) ? sdata[t - off] : 0;
    __syncthreads();
    sdata[t] += add;
    __syncthreads();
  }
  if (t < nb) partial[t] = sdata[t] - v;
  if (t == nb - 1) partial[nb] = sdata[t];
}

// rowptr[i] += partial[block]; rowptr[N] = total; zero fill for scatter
__global__ void scan_add(int* __restrict__ rowptr, const int* __restrict__ partial,
                         int* __restrict__ fill, int N) {
  int i = blockIdx.x * blockDim.x + threadIdx.x;
  if (i < N) {
    rowptr[i] += partial[i / SCAN_ELEMS];
    fill[i] = 0;
  }
  if (i == N) rowptr[N] = partial[(N + SCAN_ELEMS - 1) / SCAN_ELEMS];
}

__global__ void scatter_edges(const int* __restrict__ src, const int* __restrict__ dst,
                              const int* __restrict__ et, const int* __restrict__ rowptr,
                              int* __restrict__ fill, int* __restrict__ srcpk, int E) {
  int e = blockIdx.x * blockDim.x + threadIdx.x;
  if (e >= E) return;
  int d = dst[e];
  int pos = rowptr[d] + atomicAdd(&fill[d], 1);
  srcpk[pos] = src[e] | (et[e] << 30);
}

// ---------------- weights ----------------
// Packed bf16 W: Wpk[(k>>3)*192 + j][k&7]
__global__ void build_wpk(const float* __restrict__ basis, const float* __restrict__ comp,
                          const float* __restrict__ root, ushort* __restrict__ Wpk, int Kin) {
  int idx = blockIdx.x * blockDim.x + threadIdx.x;
  if (idx >= Kin * NCOL) return;
  int k = idx / NCOL, j = idx - k * NCOL;
  float v;
  if (j < 64) {
    v = root[k * 64 + j];
  } else {
    int r = (j >> 6) - 1, o = j & 63;
    float s = 0.f;
#pragma unroll
    for (int b = 0; b < BB; ++b)
      s = fmaf(comp[r * BB + b], basis[((size_t)b * Kin + k) * 64 + o], s);
    v = s;
  }
  Wpk[(((size_t)(k >> 3) * NCOL + j) << 3) + (k & 7)] = f2bf(v);
}

// ---------------- GEMM (MFMA bf16, K-chunked double-buffered LDS) ----------------
template <int K>
__global__ __launch_bounds__(256, 3) void gemm_mfma(const float* __restrict__ X,
                                                    const ushort* __restrict__ Wpk,
                                                    float* __restrict__ Y, int N) {
  constexpr int BK  = (K >= 128) ? 128 : K;   // K-chunk
  constexpr int NC  = K / BK;                 // chunks
  constexpr int KQC = BK / 4;                 // float4 per row per chunk
  constexpr int NLD = (64 * KQC) / 256;       // float4 loads per thread per chunk
  __shared__ ushort As[(NC > 1 ? 2 : 1) * 64 * BK];

  const int row0 = blockIdx.x * 64;
  const int tid  = threadIdx.x;
  const int wid  = tid >> 6;
  const int lane = tid & 63;
  const int lrow = lane & 15;
  const int lhi  = lane >> 4;

  float4 pf[NLD];
  // prologue: load + commit chunk 0
#pragma unroll
  for (int it = 0; it < NLD; ++it) {
    int idx = tid + it * 256;
    int row = idx / KQC, kq = idx - (idx / KQC) * KQC;
    int r = row0 + row;
    pf[it] = make_float4(0.f, 0.f, 0.f, 0.f);
    if (r < N) pf[it] = ((const float4*)X)[(size_t)r * (K / 4) + kq];
  }
#pragma unroll
  for (int it = 0; it < NLD; ++it) {
    int idx = tid + it * 256;
    int row = idx / KQC, kq = idx - (idx / KQC) * KQC;
    ushort4 b;
    b.x = f2bf(pf[it].x); b.y = f2bf(pf[it].y); b.z = f2bf(pf[it].z); b.w = f2bf(pf[it].w);
    int byte = ((row * BK + kq * 4) * 2) ^ ((row & 7) << 4);
    *(ushort4*)((char*)As + byte) = b;
  }
  __syncthreads();

  f32x4 acc[12];
#pragma unroll
  for (int c = 0; c < 12; ++c) acc[c] = (f32x4){0.f, 0.f, 0.f, 0.f};

  const int arow = wid * 16 + lrow;

  for (int c = 0; c < NC; ++c) {
    if (c + 1 < NC) {  // prefetch next chunk into regs (overlaps MFMA below)
#pragma unroll
      for (int it = 0; it < NLD; ++it) {
        int idx = tid + it * 256;
        int row = idx / KQC, kq = idx - (idx / KQC) * KQC;
        int r = row0 + row;
        pf[it] = make_float4(0.f, 0.f, 0.f, 0.f);
        if (r < N) pf[it] = ((const float4*)X)[(size_t)r * (K / 4) + (c + 1) * KQC + kq];
      }
    }
    const char* Ab = (const char*)As + (size_t)(NC > 1 ? (c & 1) : 0) * 64 * BK * 2;
#pragma unroll
    for (int t = 0; t < BK / 32; ++t) {
      int abyte = ((arow * BK + t * 32 + lhi * 8) * 2) ^ ((arow & 7) << 4);
      bf16x8 a = *(const bf16x8*)(Ab + abyte);
      const bf16x8* bp = (const bf16x8*)Wpk +
                         (size_t)(((c * (BK / 32) + t) * 4 + lhi)) * NCOL + lrow;
#pragma unroll
      for (int cc = 0; cc < 12; ++cc) {
        bf16x8 b = bp[cc * 16];
        acc[cc] = __builtin_amdgcn_mfma_f32_16x16x32_bf16(a, b, acc[cc], 0, 0, 0);
      }
    }
    if (c + 1 < NC) {
      __syncthreads();  // all waves done reading the buffer we're about to overwrite
      char* Aw = (char*)As + (size_t)((c + 1) & 1) * 64 * BK * 2;
#pragma unroll
      for (int it = 0; it < NLD; ++it) {
        int idx = tid + it * 256;
        int row = idx / KQC, kq = idx - (idx / KQC) * KQC;
        ushort4 b;
        b.x = f2bf(pf[it].x); b.y = f2bf(pf[it].y); b.z = f2bf(pf[it].z); b.w = f2bf(pf[it].w);
        int byte = ((row * BK + kq * 4) * 2) ^ ((row & 7) << 4);
        *(ushort4*)(Aw + byte) = b;
      }
      __syncthreads();
    }
  }

  // C/D: col = lane&15, row = (lane>>4)*4 + reg   [m89]
#pragma unroll
  for (int c = 0; c < 12; ++c) {
#pragma unroll
    for (int j = 0; j < 4; ++j) {
      int r = row0 + wid * 16 + lhi * 4 + j;
      if (r < N) Y[(size_t)r * NCOL + c * 16 + lrow] = acc[c][j];
    }
  }
}

// ---------------- fused per-node aggregation ----------------
// wave per node, lane per feature. res = root + bias + mean_r0 + mean_r1 (+relu)
// GATH: also hval[n] = dot(res, gw) via shuffle reduce (acc2 never materialized)
template <int RELU, int GATH>
__global__ __launch_bounds__(256) void fused_agg(const float* __restrict__ Y,
                                                 const int* __restrict__ rowptr,
                                                 const int* __restrict__ srcpk,
                                                 const float* __restrict__ bias,
                                                 const float* __restrict__ gw,
                                                 float* __restrict__ accout,
                                                 float* __restrict__ hval, int N) {
  int n = blockIdx.x * 4 + (threadIdx.x >> 6);
  if (n >= N) return;
  int lane = threadIdx.x & 63;
  float a0 = 0.f, a1 = 0.f;
  int c0 = 0, c1 = 0;
  int beg = rowptr[n], end = rowptr[n + 1];
  int i = beg;
  for (; i + 3 < end; i += 4) {  // 4 outstanding gathers
    int pk[4];
    float v[4];
#pragma unroll
    for (int u = 0; u < 4; ++u) pk[u] = srcpk[i + u];
#pragma unroll
    for (int u = 0; u < 4; ++u) {
      int s = pk[u] & 0x3fffffff, r = pk[u] >> 30;
      v[u] = Y[(size_t)s * NCOL + 64 + (r << 6) + lane];
    }
#pragma unroll
    for (int u = 0; u < 4; ++u) {
      if (pk[u] >> 30) { a1 += v[u]; c1++; } else { a0 += v[u]; c0++; }
    }
  }
  for (; i < end; ++i) {
    int pk = srcpk[i];
    int s = pk & 0x3fffffff, r = pk >> 30;
    float v = Y[(size_t)s * NCOL + 64 + (r << 6) + lane];
    if (r) { a1 += v; c1++; } else { a0 += v; c0++; }
  }
  float res = Y[(size_t)n * NCOL + lane] + bias[lane]
            + a0 / (float)(c0 > 1 ? c0 : 1) + a1 / (float)(c1 > 1 ? c1 : 1);
  if (RELU) res = fmaxf(res, 0.f);
  if (accout) accout[(size_t)n * 64 + lane] = res;
  if (GATH) {
    float v = res * gw[lane];
#pragma unroll
    for (int o = 32; o > 0; o >>= 1) v += __shfl_down(v, o);
    if (lane == 0) hval[n] = v;
  }
}

// ---------------- GAT (CSR, thread per node) ----------------
__device__ __forceinline__ float leaky(float x) { return x > 0.f ? x : 0.2f * x; }

__global__ __launch_bounds__(256) void gat_csr(const int* __restrict__ rowptr,
                                               const int* __restrict__ srcpk,
                                               const float* __restrict__ hval,
                                               const float* __restrict__ as_,
                                               const float* __restrict__ ad_,
                                               const float* __restrict__ gb,
                                               float* __restrict__ out, int N) {
  int n = blockIdx.x * blockDim.x + threadIdx.x;
  if (n >= N) return;
  float as = *as_, ad = *ad_;
  float hv = hval[n];
  float adn = hv * ad;
  float eself = leaky(hv * as + adn);
  float m = eself;
  int beg = rowptr[n], end = rowptr[n + 1];
  for (int i = beg; i < end; ++i) {
    int s = srcpk[i] & 0x3fffffff;
    float e = leaky(hval[s] * as + adn);
    m = fmaxf(m, e);
  }
  float den = expf(eself - m);
  float acc = den * hv;
  for (int i = beg; i < end; ++i) {
    int s = srcpk[i] & 0x3fffffff;
    float hs = hval[s];
    float e = leaky(hs * as + adn);
    float ex = expf(e - m);
    den += ex;
    acc += ex * hs;
  }
  out[n] = acc / den + *gb;
}

// ---------------- launch ----------------
extern "C" void kernel_launch(void* const* d_in, const int* in_sizes, int n_in,
                              void* d_out, int out_size, void* d_ws, size_t ws_size,
                              hipStream_t stream) {
  const float* x      = (const float*)d_in[0];
  const int*   eidx   = (const int*)d_in[1];
  const int*   etype  = (const int*)d_in[2];
  const float* basis1 = (const float*)d_in[3];
  const float* comp1  = (const float*)d_in[4];
  const float* root1  = (const float*)d_in[5];
  const float* bias1  = (const float*)d_in[6];
  const float* basis2 = (const float*)d_in[7];
  const float* comp2  = (const float*)d_in[8];
  const float* root2  = (const float*)d_in[9];
  const float* bias2  = (const float*)d_in[10];
  const float* gat_w  = (const float*)d_in[11];
  const float* att_s  = (const float*)d_in[12];
  const float* att_d  = (const float*)d_in[13];
  const float* gat_b  = (const float*)d_in[14];

  const int N = in_sizes[0] / 512;   // 100000
  const int E = in_sizes[1] / 2;     // 1600000
  const int* src = eidx;
  const int* dst = eidx + E;

  // workspace carve-up (16B-aligned segments)
  char* p = (char*)d_ws;
  float* Y    = (float*)p; p += (size_t)N * NCOL * 4;          // 76.8 MB
  float* acc1 = (float*)p; p += (size_t)N * 64 * 4;            // 25.6 MB
  ushort* Wpk = (ushort*)p; p += (size_t)512 * NCOL * 2;       // 0.2 MB
  float* hval = (float*)p; p += (size_t)N * 4;
  int* deg    = (int*)p;   p += (size_t)N * 4;                 // reused as fill
  int* rowptr = (int*)p;   p += (size_t)(N + 16) * 4;
  int* partial= (int*)p;   p += (size_t)(SCAN_T + 16) * 4;
  int* srcpk  = (int*)p;   p += (size_t)E * 4;                 // 6.4 MB
  float* out  = (float*)d_out;
  int* fill   = deg;

  const int TB = 256;
  const int GB = (N + 63) / 64;
  const int nb = (N + SCAN_ELEMS - 1) / SCAN_ELEMS;

  // ---- CSR build (shared by both layers and GAT) ----
  zero_int<<<(N + TB - 1) / TB, TB, 0, stream>>>(deg, N);
  hist_deg<<<(E + TB - 1) / TB, TB, 0, stream>>>(dst, deg, E);
  scan_local<<<nb, SCAN_T, 0, stream>>>(deg, rowptr, partial, N);
  scan_partial<<<1, SCAN_T, 0, stream>>>(partial, nb);
  scan_add<<<(N + 1 + TB - 1) / TB, TB, 0, stream>>>(rowptr, partial, fill, N);
  scatter_edges<<<(E + TB - 1) / TB, TB, 0, stream>>>(src, dst, etype, rowptr, fill, srcpk, E);

  // ---- layer 1 (K=512) ----
  build_wpk<<<(512 * NCOL + TB - 1) / TB, TB, 0, stream>>>(basis1, comp1, root1, Wpk, 512);
  gemm_mfma<512><<<GB, 256, 0, stream>>>(x, Wpk, Y, N);
  fused_agg<1, 0><<<(N + 3) / 4, TB, 0, stream>>>(Y, rowptr, srcpk, bias1, nullptr, acc1,
                                                  nullptr, N);

  // ---- layer 2 (K=64) ----
  build_wpk<<<(64 * NCOL + TB - 1) / TB, TB, 0, stream>>>(basis2, comp2, root2, Wpk, 64);
  gemm_mfma<64><<<GB, 256, 0, stream>>>(acc1, Wpk, Y, N);
  fused_agg<0, 1><<<(N + 3) / 4, TB, 0, stream>>>(Y, rowptr, srcpk, bias2, gat_w, nullptr,
                                                  hval, N);

  // ---- GAT ----
  gat_csr<<<(N + TB - 1) / TB, TB, 0, stream>>>(rowptr, srcpk, hval, att_s, att_d, gat_b,
                                                out, N);
}

// Round 5
// 446.237 us; speedup vs baseline: 4.0510x; 1.1228x over previous
//
#include <hip/hip_runtime.h>
#include <hip/hip_bf16.h>
#include <math.h>

#define NCOL 192   // 64 root | 64 rel0 | 64 rel1
#define BB   30    // bases
#define SCAN_T 256
#define SCAN_ELEMS 1024   // per scan block (4 per thread)

typedef short bf16x8 __attribute__((ext_vector_type(8)));
typedef float f32x4  __attribute__((ext_vector_type(4)));

__device__ __forceinline__ ushort f2bf(float f) {
  unsigned u = __float_as_uint(f);
  unsigned r = u + 0x7fff + ((u >> 16) & 1);   // RTNE
  return (ushort)(r >> 16);
}

// ---------------- CSR build ----------------
__global__ void zero_int(int* __restrict__ p, int n) {
  int i = blockIdx.x * blockDim.x + threadIdx.x;
  if (i < n) p[i] = 0;
}

__global__ void hist_deg(const int* __restrict__ dst, int* __restrict__ deg, int E) {
  int e = blockIdx.x * blockDim.x + threadIdx.x;
  if (e >= E) return;
  atomicAdd(&deg[dst[e]], 1);
}

// per-block exclusive scan of deg -> rowptr[0..N), block totals -> partial[b]
__global__ __launch_bounds__(SCAN_T) void scan_local(const int* __restrict__ deg,
                                                     int* __restrict__ rowptr,
                                                     int* __restrict__ partial, int N) {
  __shared__ int sdata[SCAN_T];
  int t = threadIdx.x;
  int base = blockIdx.x * SCAN_ELEMS + t * 4;
  int v[4], s = 0;
#pragma unroll
  for (int k = 0; k < 4; ++k) {
    v[k] = (base + k < N) ? deg[base + k] : 0;
    s += v[k];
  }
  sdata[t] = s;
  __syncthreads();
  for (int off = 1; off < SCAN_T; off <<= 1) {
    int add = (t >= off) ? sdata[t - off] : 0;
    __syncthreads();
    sdata[t] += add;
    __syncthreads();
  }
  int run = sdata[t] - s;  // exclusive prefix of this thread's chunk
  if (t == SCAN_T - 1) partial[blockIdx.x] = sdata[t];
#pragma unroll
  for (int k = 0; k < 4; ++k) {
    if (base + k < N) rowptr[base + k] = run;
    run += v[k];
  }
}

// single-block exclusive scan of partial[0..nb), total appended at partial[nb]
__global__ __launch_bounds__(SCAN_T) void scan_partial(int* __restrict__ partial, int nb) {
  __shared__ int sdata[SCAN_T];
  int t = threadIdx.x;
  int v = (t < nb) ? partial[t] : 0;
  sdata[t] = v;
  __syncthreads();
  for (int off = 1; off < SCAN_T; off <<= 1) {
    int add = (t >= off) ? sdata[t - off] : 0;
    __syncthreads();
    sdata[t] += add;
    __syncthreads();
  }
  if (t < nb) partial[t] = sdata[t] - v;
  if (t == nb - 1) partial[nb] = sdata[t];
}

// rowptr[i] += partial[block]; rowptr[N] = total; zero fill for scatter
__global__ void scan_add(int* __restrict__ rowptr, const int* __restrict__ partial,
                         int* __restrict__ fill, int N) {
  int i = blockIdx.x * blockDim.x + threadIdx.x;
  if (i < N) {
    rowptr[i] += partial[i / SCAN_ELEMS];
    fill[i] = 0;
  }
  if (i == N) rowptr[N] = partial[(N + SCAN_ELEMS - 1) / SCAN_ELEMS];
}

__global__ void scatter_edges(const int* __restrict__ src, const int* __restrict__ dst,
                              const int* __restrict__ et, const int* __restrict__ rowptr,
                              int* __restrict__ fill, int* __restrict__ srcpk, int E) {
  int e = blockIdx.x * blockDim.x + threadIdx.x;
  if (e >= E) return;
  int d = dst[e];
  int pos = rowptr[d] + atomicAdd(&fill[d], 1);
  srcpk[pos] = src[e] | (et[e] << 30);
}

// ---------------- weights ----------------
// Packed bf16 W: Wpk[(k>>3)*192 + j][k&7]
__global__ void build_wpk(const float* __restrict__ basis, const float* __restrict__ comp,
                          const float* __restrict__ root, ushort* __restrict__ Wpk, int Kin) {
  int idx = blockIdx.x * blockDim.x + threadIdx.x;
  if (idx >= Kin * NCOL) return;
  int k = idx / NCOL, j = idx - k * NCOL;
  float v;
  if (j < 64) {
    v = root[k * 64 + j];
  } else {
    int r = (j >> 6) - 1, o = j & 63;
    float s = 0.f;
#pragma unroll
    for (int b = 0; b < BB; ++b)
      s = fmaf(comp[r * BB + b], basis[((size_t)b * Kin + k) * 64 + o], s);
    v = s;
  }
  Wpk[(((size_t)(k >> 3) * NCOL + j) << 3) + (k & 7)] = f2bf(v);
}

// ---------------- GEMM (MFMA bf16, split-col waves, K-chunked dbuf LDS) ----------------
// Block: 64 rows x 192 cols. Wave w owns cols [48w, 48w+48): 3 B-frags x 4 A-frags.
// B is read from L2 exactly once per block (no inter-wave redundancy).
template <int K>
__global__ __launch_bounds__(256, 3) void gemm_mfma(const float* __restrict__ X,
                                                    const ushort* __restrict__ Wpk,
                                                    float* __restrict__ Y, int N) {
  constexpr int BK  = (K >= 128) ? 128 : K;   // K-chunk
  constexpr int NC  = K / BK;                 // chunks
  constexpr int KQC = BK / 4;                 // float4 per row per chunk
  constexpr int NLD = (64 * KQC) / 256;       // float4 loads per thread per chunk
  __shared__ ushort As[(NC > 1 ? 2 : 1) * 64 * BK];

  const int row0 = blockIdx.x * 64;
  const int tid  = threadIdx.x;
  const int wid  = tid >> 6;
  const int lane = tid & 63;
  const int lrow = lane & 15;
  const int lhi  = lane >> 4;

  float4 pf[NLD];
  // prologue: load + commit chunk 0
#pragma unroll
  for (int it = 0; it < NLD; ++it) {
    int idx = tid + it * 256;
    int row = idx / KQC, kq = idx - (idx / KQC) * KQC;
    int r = row0 + row;
    pf[it] = make_float4(0.f, 0.f, 0.f, 0.f);
    if (r < N) pf[it] = ((const float4*)X)[(size_t)r * (K / 4) + kq];
  }
#pragma unroll
  for (int it = 0; it < NLD; ++it) {
    int idx = tid + it * 256;
    int row = idx / KQC, kq = idx - (idx / KQC) * KQC;
    ushort4 b;
    b.x = f2bf(pf[it].x); b.y = f2bf(pf[it].y); b.z = f2bf(pf[it].z); b.w = f2bf(pf[it].w);
    int byte = ((row * BK + kq * 4) * 2) ^ ((row & 7) << 4);
    *(ushort4*)((char*)As + byte) = b;
  }
  __syncthreads();

  f32x4 acc[4][3];
#pragma unroll
  for (int s = 0; s < 4; ++s)
#pragma unroll
    for (int c = 0; c < 3; ++c) acc[s][c] = (f32x4){0.f, 0.f, 0.f, 0.f};

  for (int c = 0; c < NC; ++c) {
    if (c + 1 < NC) {  // prefetch next chunk into regs (overlaps MFMA below)
#pragma unroll
      for (int it = 0; it < NLD; ++it) {
        int idx = tid + it * 256;
        int row = idx / KQC, kq = idx - (idx / KQC) * KQC;
        int r = row0 + row;
        pf[it] = make_float4(0.f, 0.f, 0.f, 0.f);
        if (r < N) pf[it] = ((const float4*)X)[(size_t)r * (K / 4) + (c + 1) * KQC + kq];
      }
    }
    const char* Ab = (const char*)As + (size_t)(NC > 1 ? (c & 1) : 0) * 64 * BK * 2;
#pragma unroll
    for (int t = 0; t < BK / 32; ++t) {
      int g = (c * (BK / 32) + t) * 4 + lhi;  // bf16x8 k-group index
      const bf16x8* bp = (const bf16x8*)Wpk + (size_t)g * NCOL + wid * 48 + lrow;
      bf16x8 b0 = bp[0];
      bf16x8 b1 = bp[16];
      bf16x8 b2 = bp[32];
      bf16x8 a[4];
#pragma unroll
      for (int s = 0; s < 4; ++s) {
        int arow = s * 16 + lrow;
        int abyte = ((arow * BK + t * 32 + lhi * 8) * 2) ^ ((arow & 7) << 4);
        a[s] = *(const bf16x8*)(Ab + abyte);
      }
#pragma unroll
      for (int s = 0; s < 4; ++s) {
        acc[s][0] = __builtin_amdgcn_mfma_f32_16x16x32_bf16(a[s], b0, acc[s][0], 0, 0, 0);
        acc[s][1] = __builtin_amdgcn_mfma_f32_16x16x32_bf16(a[s], b1, acc[s][1], 0, 0, 0);
        acc[s][2] = __builtin_amdgcn_mfma_f32_16x16x32_bf16(a[s], b2, acc[s][2], 0, 0, 0);
      }
    }
    if (c + 1 < NC) {
      __syncthreads();  // all waves done reading the buffer we're about to overwrite
      char* Aw = (char*)As + (size_t)((c + 1) & 1) * 64 * BK * 2;
#pragma unroll
      for (int it = 0; it < NLD; ++it) {
        int idx = tid + it * 256;
        int row = idx / KQC, kq = idx - (idx / KQC) * KQC;
        ushort4 b;
        b.x = f2bf(pf[it].x); b.y = f2bf(pf[it].y); b.z = f2bf(pf[it].z); b.w = f2bf(pf[it].w);
        int byte = ((row * BK + kq * 4) * 2) ^ ((row & 7) << 4);
        *(ushort4*)(Aw + byte) = b;
      }
      __syncthreads();
    }
  }

  // C/D: col = lane&15, row = (lane>>4)*4 + reg   [m89]
#pragma unroll
  for (int s = 0; s < 4; ++s) {
#pragma unroll
    for (int cc = 0; cc < 3; ++cc) {
#pragma unroll
      for (int j = 0; j < 4; ++j) {
        int r = row0 + s * 16 + lhi * 4 + j;
        if (r < N) Y[(size_t)r * NCOL + wid * 48 + cc * 16 + lrow] = acc[s][cc][j];
      }
    }
  }
}

// ---------------- fused per-node aggregation ----------------
// wave per node, lane per feature. res = root + bias + mean_r0 + mean_r1 (+relu)
// GATH: also hval[n] = dot(res, gw) via shuffle reduce (acc2 never materialized)
template <int RELU, int GATH>
__global__ __launch_bounds__(256) void fused_agg(const float* __restrict__ Y,
                                                 const int* __restrict__ rowptr,
                                                 const int* __restrict__ srcpk,
                                                 const float* __restrict__ bias,
                                                 const float* __restrict__ gw,
                                                 float* __restrict__ accout,
                                                 float* __restrict__ hval, int N) {
  int n = blockIdx.x * 4 + (threadIdx.x >> 6);
  if (n >= N) return;
  int lane = threadIdx.x & 63;
  float a0 = 0.f, a1 = 0.f;
  int c0 = 0, c1 = 0;
  int beg = rowptr[n], end = rowptr[n + 1];
  int i = beg;
  for (; i + 3 < end; i += 4) {  // 4 outstanding gathers
    int pk[4];
    float v[4];
#pragma unroll
    for (int u = 0; u < 4; ++u) pk[u] = srcpk[i + u];
#pragma unroll
    for (int u = 0; u < 4; ++u) {
      int s = pk[u] & 0x3fffffff, r = pk[u] >> 30;
      v[u] = Y[(size_t)s * NCOL + 64 + (r << 6) + lane];
    }
#pragma unroll
    for (int u = 0; u < 4; ++u) {
      if (pk[u] >> 30) { a1 += v[u]; c1++; } else { a0 += v[u]; c0++; }
    }
  }
  for (; i < end; ++i) {
    int pk = srcpk[i];
    int s = pk & 0x3fffffff, r = pk >> 30;
    float v = Y[(size_t)s * NCOL + 64 + (r << 6) + lane];
    if (r) { a1 += v; c1++; } else { a0 += v; c0++; }
  }
  float res = Y[(size_t)n * NCOL + lane] + bias[lane]
            + a0 / (float)(c0 > 1 ? c0 : 1) + a1 / (float)(c1 > 1 ? c1 : 1);
  if (RELU) res = fmaxf(res, 0.f);
  if (accout) accout[(size_t)n * 64 + lane] = res;
  if (GATH) {
    float v = res * gw[lane];
#pragma unroll
    for (int o = 32; o > 0; o >>= 1) v += __shfl_down(v, o);
    if (lane == 0) hval[n] = v;
  }
}

// ---------------- GAT (CSR, thread per node) ----------------
__device__ __forceinline__ float leaky(float x) { return x > 0.f ? x : 0.2f * x; }

__global__ __launch_bounds__(256) void gat_csr(const int* __restrict__ rowptr,
                                               const int* __restrict__ srcpk,
                                               const float* __restrict__ hval,
                                               const float* __restrict__ as_,
                                               const float* __restrict__ ad_,
                                               const float* __restrict__ gb,
                                               float* __restrict__ out, int N) {
  int n = blockIdx.x * blockDim.x + threadIdx.x;
  if (n >= N) return;
  float as = *as_, ad = *ad_;
  float hv = hval[n];
  float adn = hv * ad;
  float eself = leaky(hv * as + adn);
  float m = eself;
  int beg = rowptr[n], end = rowptr[n + 1];
  for (int i = beg; i < end; ++i) {
    int s = srcpk[i] & 0x3fffffff;
    float e = leaky(hval[s] * as + adn);
    m = fmaxf(m, e);
  }
  float den = expf(eself - m);
  float acc = den * hv;
  for (int i = beg; i < end; ++i) {
    int s = srcpk[i] & 0x3fffffff;
    float hs = hval[s];
    float e = leaky(hs * as + adn);
    float ex = expf(e - m);
    den += ex;
    acc += ex * hs;
  }
  out[n] = acc / den + *gb;
}

// ---------------- launch ----------------
extern "C" void kernel_launch(void* const* d_in, const int* in_sizes, int n_in,
                              void* d_out, int out_size, void* d_ws, size_t ws_size,
                              hipStream_t stream) {
  const float* x      = (const float*)d_in[0];
  const int*   eidx   = (const int*)d_in[1];
  const int*   etype  = (const int*)d_in[2];
  const float* basis1 = (const float*)d_in[3];
  const float* comp1  = (const float*)d_in[4];
  const float* root1  = (const float*)d_in[5];
  const float* bias1  = (const float*)d_in[6];
  const float* basis2 = (const float*)d_in[7];
  const float* comp2  = (const float*)d_in[8];
  const float* root2  = (const float*)d_in[9];
  const float* bias2  = (const float*)d_in[10];
  const float* gat_w  = (const float*)d_in[11];
  const float* att_s  = (const float*)d_in[12];
  const float* att_d  = (const float*)d_in[13];
  const float* gat_b  = (const float*)d_in[14];

  const int N = in_sizes[0] / 512;   // 100000
  const int E = in_sizes[1] / 2;     // 1600000
  const int* src = eidx;
  const int* dst = eidx + E;

  // workspace carve-up (16B-aligned segments)
  char* p = (char*)d_ws;
  float* Y    = (float*)p; p += (size_t)N * NCOL * 4;          // 76.8 MB
  float* acc1 = (float*)p; p += (size_t)N * 64 * 4;            // 25.6 MB
  ushort* Wpk = (ushort*)p; p += (size_t)512 * NCOL * 2;       // 0.2 MB
  float* hval = (float*)p; p += (size_t)N * 4;
  int* deg    = (int*)p;   p += (size_t)N * 4;                 // reused as fill
  int* rowptr = (int*)p;   p += (size_t)(N + 16) * 4;
  int* partial= (int*)p;   p += (size_t)(SCAN_T + 16) * 4;
  int* srcpk  = (int*)p;   p += (size_t)E * 4;                 // 6.4 MB
  float* out  = (float*)d_out;
  int* fill   = deg;

  const int TB = 256;
  const int GB = (N + 63) / 64;
  const int nb = (N + SCAN_ELEMS - 1) / SCAN_ELEMS;

  // ---- CSR build (shared by both layers and GAT) ----
  zero_int<<<(N + TB - 1) / TB, TB, 0, stream>>>(deg, N);
  hist_deg<<<(E + TB - 1) / TB, TB, 0, stream>>>(dst, deg, E);
  scan_local<<<nb, SCAN_T, 0, stream>>>(deg, rowptr, partial, N);
  scan_partial<<<1, SCAN_T, 0, stream>>>(partial, nb);
  scan_add<<<(N + 1 + TB - 1) / TB, TB, 0, stream>>>(rowptr, partial, fill, N);
  scatter_edges<<<(E + TB - 1) / TB, TB, 0, stream>>>(src, dst, etype, rowptr, fill, srcpk, E);

  // ---- layer 1 (K=512) ----
  build_wpk<<<(512 * NCOL + TB - 1) / TB, TB, 0, stream>>>(basis1, comp1, root1, Wpk, 512);
  gemm_mfma<512><<<GB, 256, 0, stream>>>(x, Wpk, Y, N);
  fused_agg<1, 0><<<(N + 3) / 4, TB, 0, stream>>>(Y, rowptr, srcpk, bias1, nullptr, acc1,
                                                  nullptr, N);

  // ---- layer 2 (K=64) ----
  build_wpk<<<(64 * NCOL + TB - 1) / TB, TB, 0, stream>>>(basis2, comp2, root2, Wpk, 64);
  gemm_mfma<64><<<GB, 256, 0, stream>>>(acc1, Wpk, Y, N);
  fused_agg<0, 1><<<(N + 3) / 4, TB, 0, stream>>>(Y, rowptr, srcpk, bias2, gat_w, nullptr,
                                                  hval, N);

  // ---- GAT ----
  gat_csr<<<(N + TB - 1) / TB, TB, 0, stream>>>(rowptr, srcpk, hval, att_s, att_d, gat_b,
                                                out, N);
}

// Round 6
// 431.361 us; speedup vs baseline: 4.1907x; 1.0345x over previous
//
#include <hip/hip_runtime.h>
#include <hip/hip_bf16.h>
#include <math.h>

#define NCOL 192   // 64 root | 64 rel0 | 64 rel1
#define BB   30    // bases
#define SCAN_T 256
#define SCAN_ELEMS 1024   // per scan block (4 per thread)

typedef short bf16x8 __attribute__((ext_vector_type(8)));
typedef float f32x4  __attribute__((ext_vector_type(4)));
typedef unsigned short u16x8 __attribute__((ext_vector_type(8)));

__device__ __forceinline__ ushort f2bf(float f) {
  unsigned u = __float_as_uint(f);
  unsigned r = u + 0x7fff + ((u >> 16) & 1);   // RTNE
  return (ushort)(r >> 16);
}
__device__ __forceinline__ float bf2f(ushort u) {
  return __uint_as_float(((unsigned)u) << 16);
}

// ---------------- CSR build ----------------
__global__ void zero_int(int* __restrict__ p, int n) {
  int i = blockIdx.x * blockDim.x + threadIdx.x;
  if (i < n) p[i] = 0;
}

__global__ void hist_deg(const int* __restrict__ dst, int* __restrict__ deg, int E) {
  int e = blockIdx.x * blockDim.x + threadIdx.x;
  if (e >= E) return;
  atomicAdd(&deg[dst[e]], 1);
}

// per-block exclusive scan of deg -> rowptr[0..N), block totals -> partial[b]
__global__ __launch_bounds__(SCAN_T) void scan_local(const int* __restrict__ deg,
                                                     int* __restrict__ rowptr,
                                                     int* __restrict__ partial, int N) {
  __shared__ int sdata[SCAN_T];
  int t = threadIdx.x;
  int base = blockIdx.x * SCAN_ELEMS + t * 4;
  int v[4], s = 0;
#pragma unroll
  for (int k = 0; k < 4; ++k) {
    v[k] = (base + k < N) ? deg[base + k] : 0;
    s += v[k];
  }
  sdata[t] = s;
  __syncthreads();
  for (int off = 1; off < SCAN_T; off <<= 1) {
    int add = (t >= off) ? sdata[t - off] : 0;
    __syncthreads();
    sdata[t] += add;
    __syncthreads();
  }
  int run = sdata[t] - s;  // exclusive prefix of this thread's chunk
  if (t == SCAN_T - 1) partial[blockIdx.x] = sdata[t];
#pragma unroll
  for (int k = 0; k < 4; ++k) {
    if (base + k < N) rowptr[base + k] = run;
    run += v[k];
  }
}

// single-block exclusive scan of partial[0..nb), total appended at partial[nb]
__global__ __launch_bounds__(SCAN_T) void scan_partial(int* __restrict__ partial, int nb) {
  __shared__ int sdata[SCAN_T];
  int t = threadIdx.x;
  int v = (t < nb) ? partial[t] : 0;
  sdata[t] = v;
  __syncthreads();
  for (int off = 1; off < SCAN_T; off <<= 1) {
    int add = (t >= off) ? sdata[t - off] : 0;
    __syncthreads();
    sdata[t] += add;
    __syncthreads();
  }
  if (t < nb) partial[t] = sdata[t] - v;
  if (t == nb - 1) partial[nb] = sdata[t];
}

// rowptr[i] += partial[block]; rowptr[N] = total; zero fill for scatter
__global__ void scan_add(int* __restrict__ rowptr, const int* __restrict__ partial,
                         int* __restrict__ fill, int N) {
  int i = blockIdx.x * blockDim.x + threadIdx.x;
  if (i < N) {
    rowptr[i] += partial[i / SCAN_ELEMS];
    fill[i] = 0;
  }
  if (i == N) rowptr[N] = partial[(N + SCAN_ELEMS - 1) / SCAN_ELEMS];
}

__global__ void scatter_edges(const int* __restrict__ src, const int* __restrict__ dst,
                              const int* __restrict__ et, const int* __restrict__ rowptr,
                              int* __restrict__ fill, int* __restrict__ srcpk, int E) {
  int e = blockIdx.x * blockDim.x + threadIdx.x;
  if (e >= E) return;
  int d = dst[e];
  int pos = rowptr[d] + atomicAdd(&fill[d], 1);
  srcpk[pos] = src[e] | (et[e] << 30);
}

// ---------------- weights ----------------
// Packed bf16 W: Wpk[(k>>3)*192 + j][k&7]
__global__ void build_wpk(const float* __restrict__ basis, const float* __restrict__ comp,
                          const float* __restrict__ root, ushort* __restrict__ Wpk, int Kin) {
  int idx = blockIdx.x * blockDim.x + threadIdx.x;
  if (idx >= Kin * NCOL) return;
  int k = idx / NCOL, j = idx - k * NCOL;
  float v;
  if (j < 64) {
    v = root[k * 64 + j];
  } else {
    int r = (j >> 6) - 1, o = j & 63;
    float s = 0.f;
#pragma unroll
    for (int b = 0; b < BB; ++b)
      s = fmaf(comp[r * BB + b], basis[((size_t)b * Kin + k) * 64 + o], s);
    v = s;
  }
  Wpk[(((size_t)(k >> 3) * NCOL + j) << 3) + (k & 7)] = f2bf(v);
}

// ---------------- GEMM (MFMA bf16, split-col waves, BK=64 dbuf LDS) ----------------
// Block: 64 rows x 192 cols. Wave w owns cols [48w, 48w+48).
// BF16IN=0: X is f32 (convert during staging); BF16IN=1: X is bf16 (direct copy).
// Y is written bf16.
template <int K, int BF16IN>
__global__ __launch_bounds__(256, 4) void gemm_mfma(const void* __restrict__ Xv,
                                                    const ushort* __restrict__ Wpk,
                                                    ushort* __restrict__ Y, int N) {
  constexpr int BK  = 64;
  constexpr int NC  = K / BK;
  constexpr int NLD = BF16IN ? (64 * (BK / 8) / 256) : (64 * (BK / 4) / 256);
  __shared__ ushort As[(NC > 1 ? 2 : 1) * 64 * BK];

  const int row0 = blockIdx.x * 64;
  const int tid  = threadIdx.x;
  const int wid  = tid >> 6;
  const int lane = tid & 63;
  const int lrow = lane & 15;
  const int lhi  = lane >> 4;

  const float*  Xf = (const float*)Xv;
  const ushort* Xh = (const ushort*)Xv;

  float4 pf[BF16IN ? 1 : NLD];
  u16x8  pfh[BF16IN ? NLD : 1];

#define LOAD_CHUNK(c)                                                              \
  if constexpr (BF16IN) {                                                          \
    _Pragma("unroll") for (int it = 0; it < NLD; ++it) {                           \
      int idx = tid + it * 256;                                                    \
      int row = idx / (BK / 8), kq = idx - row * (BK / 8);                         \
      int r = row0 + row;                                                          \
      pfh[it] = (u16x8){0, 0, 0, 0, 0, 0, 0, 0};                                   \
      if (r < N) pfh[it] = ((const u16x8*)Xh)[(size_t)r * (K / 8) + (c) * (BK / 8) + kq]; \
    }                                                                              \
  } else {                                                                         \
    _Pragma("unroll") for (int it = 0; it < NLD; ++it) {                           \
      int idx = tid + it * 256;                                                    \
      int row = idx / (BK / 4), kq = idx - row * (BK / 4);                         \
      int r = row0 + row;                                                          \
      pf[it] = make_float4(0.f, 0.f, 0.f, 0.f);                                    \
      if (r < N) pf[it] = ((const float4*)Xf)[(size_t)r * (K / 4) + (c) * (BK / 4) + kq]; \
    }                                                                              \
  }

#define COMMIT_CHUNK(buf)                                                          \
  {                                                                                \
    char* Aw = (char*)As + (size_t)(buf) * 64 * BK * 2;                            \
    if constexpr (BF16IN) {                                                        \
      _Pragma("unroll") for (int it = 0; it < NLD; ++it) {                         \
        int idx = tid + it * 256;                                                  \
        int row = idx / (BK / 8), kq = idx - row * (BK / 8);                       \
        int byte = ((row * BK + kq * 8) * 2) ^ ((row & 7) << 4);                   \
        *(u16x8*)(Aw + byte) = pfh[it];                                            \
      }                                                                            \
    } else {                                                                       \
      _Pragma("unroll") for (int it = 0; it < NLD; ++it) {                         \
        int idx = tid + it * 256;                                                  \
        int row = idx / (BK / 4), kq = idx - row * (BK / 4);                       \
        ushort4 b;                                                                 \
        b.x = f2bf(pf[it].x); b.y = f2bf(pf[it].y);                                \
        b.z = f2bf(pf[it].z); b.w = f2bf(pf[it].w);                                \
        int byte = ((row * BK + kq * 4) * 2) ^ ((row & 7) << 4);                   \
        *(ushort4*)(Aw + byte) = b;                                                \
      }                                                                            \
    }                                                                              \
  }

  // prologue: chunk 0
  LOAD_CHUNK(0)
  COMMIT_CHUNK(0)
  __syncthreads();

  f32x4 acc[4][3];
#pragma unroll
  for (int s = 0; s < 4; ++s)
#pragma unroll
    for (int c = 0; c < 3; ++c) acc[s][c] = (f32x4){0.f, 0.f, 0.f, 0.f};

  for (int c = 0; c < NC; ++c) {
    if (c + 1 < NC) { LOAD_CHUNK(c + 1) }   // overlaps MFMA below
    const char* Ab = (const char*)As + (size_t)(NC > 1 ? (c & 1) : 0) * 64 * BK * 2;
#pragma unroll
    for (int t = 0; t < BK / 32; ++t) {
      int g = (c * (BK / 32) + t) * 4 + lhi;  // bf16x8 k-group index
      const bf16x8* bp = (const bf16x8*)Wpk + (size_t)g * NCOL + wid * 48 + lrow;
      bf16x8 b0 = bp[0];
      bf16x8 b1 = bp[16];
      bf16x8 b2 = bp[32];
      bf16x8 a[4];
#pragma unroll
      for (int s = 0; s < 4; ++s) {
        int arow = s * 16 + lrow;
        int abyte = ((arow * BK + t * 32 + lhi * 8) * 2) ^ ((arow & 7) << 4);
        a[s] = *(const bf16x8*)(Ab + abyte);
      }
#pragma unroll
      for (int s = 0; s < 4; ++s) {
        acc[s][0] = __builtin_amdgcn_mfma_f32_16x16x32_bf16(a[s], b0, acc[s][0], 0, 0, 0);
        acc[s][1] = __builtin_amdgcn_mfma_f32_16x16x32_bf16(a[s], b1, acc[s][1], 0, 0, 0);
        acc[s][2] = __builtin_amdgcn_mfma_f32_16x16x32_bf16(a[s], b2, acc[s][2], 0, 0, 0);
      }
    }
    if (c + 1 < NC) {
      __syncthreads();  // all waves done reading the buffer we're about to overwrite
      COMMIT_CHUNK((c + 1) & 1)
      __syncthreads();
    }
  }
#undef LOAD_CHUNK
#undef COMMIT_CHUNK

  // C/D: col = lane&15, row = (lane>>4)*4 + reg   [m89]
#pragma unroll
  for (int s = 0; s < 4; ++s) {
#pragma unroll
    for (int cc = 0; cc < 3; ++cc) {
#pragma unroll
      for (int j = 0; j < 4; ++j) {
        int r = row0 + s * 16 + lhi * 4 + j;
        if (r < N) Y[(size_t)r * NCOL + wid * 48 + cc * 16 + lrow] = f2bf(acc[s][cc][j]);
      }
    }
  }
}

// ---------------- fused per-node aggregation ----------------
// wave per node, lane per feature. res = root + bias + mean_r0 + mean_r1 (+relu)
// Y is bf16; accout (bf16) written when non-null; GATH: hval = dot(res, gw).
template <int RELU, int GATH>
__global__ __launch_bounds__(256) void fused_agg(const ushort* __restrict__ Y,
                                                 const int* __restrict__ rowptr,
                                                 const int* __restrict__ srcpk,
                                                 const float* __restrict__ bias,
                                                 const float* __restrict__ gw,
                                                 ushort* __restrict__ accout,
                                                 float* __restrict__ hval, int N) {
  int n = blockIdx.x * 4 + (threadIdx.x >> 6);
  if (n >= N) return;
  int lane = threadIdx.x & 63;
  float a0 = 0.f, a1 = 0.f;
  int c0 = 0, c1 = 0;
  int beg = rowptr[n], end = rowptr[n + 1];
  int i = beg;
  for (; i + 3 < end; i += 4) {  // 4 outstanding gathers
    int pk[4];
    float v[4];
#pragma unroll
    for (int u = 0; u < 4; ++u) pk[u] = srcpk[i + u];
#pragma unroll
    for (int u = 0; u < 4; ++u) {
      int s = pk[u] & 0x3fffffff, r = pk[u] >> 30;
      v[u] = bf2f(Y[(size_t)s * NCOL + 64 + (r << 6) + lane]);
    }
#pragma unroll
    for (int u = 0; u < 4; ++u) {
      if (pk[u] >> 30) { a1 += v[u]; c1++; } else { a0 += v[u]; c0++; }
    }
  }
  for (; i < end; ++i) {
    int pk = srcpk[i];
    int s = pk & 0x3fffffff, r = pk >> 30;
    float v = bf2f(Y[(size_t)s * NCOL + 64 + (r << 6) + lane]);
    if (r) { a1 += v; c1++; } else { a0 += v; c0++; }
  }
  float res = bf2f(Y[(size_t)n * NCOL + lane]) + bias[lane]
            + a0 / (float)(c0 > 1 ? c0 : 1) + a1 / (float)(c1 > 1 ? c1 : 1);
  if (RELU) res = fmaxf(res, 0.f);
  if (accout) accout[(size_t)n * 64 + lane] = f2bf(res);
  if (GATH) {
    float v = res * gw[lane];
#pragma unroll
    for (int o = 32; o > 0; o >>= 1) v += __shfl_down(v, o);
    if (lane == 0) hval[n] = v;
  }
}

// ---------------- GAT (CSR, thread per node) ----------------
__device__ __forceinline__ float leaky(float x) { return x > 0.f ? x : 0.2f * x; }

__global__ __launch_bounds__(256) void gat_csr(const int* __restrict__ rowptr,
                                               const int* __restrict__ srcpk,
                                               const float* __restrict__ hval,
                                               const float* __restrict__ as_,
                                               const float* __restrict__ ad_,
                                               const float* __restrict__ gb,
                                               float* __restrict__ out, int N) {
  int n = blockIdx.x * blockDim.x + threadIdx.x;
  if (n >= N) return;
  float as = *as_, ad = *ad_;
  float hv = hval[n];
  float adn = hv * ad;
  float eself = leaky(hv * as + adn);
  float m = eself;
  int beg = rowptr[n], end = rowptr[n + 1];
  for (int i = beg; i < end; ++i) {
    int s = srcpk[i] & 0x3fffffff;
    float e = leaky(hval[s] * as + adn);
    m = fmaxf(m, e);
  }
  float den = expf(eself - m);
  float acc = den * hv;
  for (int i = beg; i < end; ++i) {
    int s = srcpk[i] & 0x3fffffff;
    float hs = hval[s];
    float e = leaky(hs * as + adn);
    float ex = expf(e - m);
    den += ex;
    acc += ex * hs;
  }
  out[n] = acc / den + *gb;
}

// ---------------- launch ----------------
extern "C" void kernel_launch(void* const* d_in, const int* in_sizes, int n_in,
                              void* d_out, int out_size, void* d_ws, size_t ws_size,
                              hipStream_t stream) {
  const float* x      = (const float*)d_in[0];
  const int*   eidx   = (const int*)d_in[1];
  const int*   etype  = (const int*)d_in[2];
  const float* basis1 = (const float*)d_in[3];
  const float* comp1  = (const float*)d_in[4];
  const float* root1  = (const float*)d_in[5];
  const float* bias1  = (const float*)d_in[6];
  const float* basis2 = (const float*)d_in[7];
  const float* comp2  = (const float*)d_in[8];
  const float* root2  = (const float*)d_in[9];
  const float* bias2  = (const float*)d_in[10];
  const float* gat_w  = (const float*)d_in[11];
  const float* att_s  = (const float*)d_in[12];
  const float* att_d  = (const float*)d_in[13];
  const float* gat_b  = (const float*)d_in[14];

  const int N = in_sizes[0] / 512;   // 100000
  const int E = in_sizes[1] / 2;     // 1600000
  const int* src = eidx;
  const int* dst = eidx + E;

  // workspace carve-up (16B-aligned segments)
  char* p = (char*)d_ws;
  ushort* Y    = (ushort*)p; p += (size_t)N * NCOL * 2;        // 38.4 MB (bf16)
  ushort* acc1 = (ushort*)p; p += (size_t)N * 64 * 2;          // 12.8 MB (bf16)
  ushort* Wpk  = (ushort*)p; p += (size_t)512 * NCOL * 2;      // 0.2 MB
  float* hval  = (float*)p;  p += (size_t)N * 4;
  int* deg     = (int*)p;    p += (size_t)N * 4;               // reused as fill
  int* rowptr  = (int*)p;    p += (size_t)(N + 16) * 4;
  int* partial = (int*)p;    p += (size_t)(SCAN_T + 16) * 4;
  int* srcpk   = (int*)p;    p += (size_t)E * 4;               // 6.4 MB
  float* out   = (float*)d_out;
  int* fill    = deg;

  const int TB = 256;
  const int GB = (N + 63) / 64;
  const int nb = (N + SCAN_ELEMS - 1) / SCAN_ELEMS;

  // ---- CSR build (shared by both layers and GAT) ----
  zero_int<<<(N + TB - 1) / TB, TB, 0, stream>>>(deg, N);
  hist_deg<<<(E + TB - 1) / TB, TB, 0, stream>>>(dst, deg, E);
  scan_local<<<nb, SCAN_T, 0, stream>>>(deg, rowptr, partial, N);
  scan_partial<<<1, SCAN_T, 0, stream>>>(partial, nb);
  scan_add<<<(N + 1 + TB - 1) / TB, TB, 0, stream>>>(rowptr, partial, fill, N);
  scatter_edges<<<(E + TB - 1) / TB, TB, 0, stream>>>(src, dst, etype, rowptr, fill, srcpk, E);

  // ---- layer 1 (K=512, f32 input) ----
  build_wpk<<<(512 * NCOL + TB - 1) / TB, TB, 0, stream>>>(basis1, comp1, root1, Wpk, 512);
  gemm_mfma<512, 0><<<GB, 256, 0, stream>>>(x, Wpk, Y, N);
  fused_agg<1, 0><<<(N + 3) / 4, TB, 0, stream>>>(Y, rowptr, srcpk, bias1, nullptr, acc1,
                                                  nullptr, N);

  // ---- layer 2 (K=64, bf16 input) ----
  build_wpk<<<(64 * NCOL + TB - 1) / TB, TB, 0, stream>>>(basis2, comp2, root2, Wpk, 64);
  gemm_mfma<64, 1><<<GB, 256, 0, stream>>>(acc1, Wpk, Y, N);
  fused_agg<0, 1><<<(N + 3) / 4, TB, 0, stream>>>(Y, rowptr, srcpk, bias2, gat_w, nullptr,
                                                  hval, N);

  // ---- GAT ----
  gat_csr<<<(N + TB - 1) / TB, TB, 0, stream>>>(rowptr, srcpk, hval, att_s, att_d, gat_b,
                                                out, N);
}

// Round 7
// 410.676 us; speedup vs baseline: 4.4018x; 1.0504x over previous
//
#include <hip/hip_runtime.h>
#include <hip/hip_bf16.h>
#include <math.h>

#define NCOL 192   // 64 root | 64 rel0 | 64 rel1
#define BB   30    // bases
#define SCAN_T 256
#define SCAN_ELEMS 1024   // per scan block (4 per thread)

typedef short bf16x8 __attribute__((ext_vector_type(8)));
typedef float f32x4  __attribute__((ext_vector_type(4)));
typedef unsigned short u16x8 __attribute__((ext_vector_type(8)));

__device__ __forceinline__ ushort f2bf(float f) {
  unsigned u = __float_as_uint(f);
  unsigned r = u + 0x7fff + ((u >> 16) & 1);   // RTNE
  return (ushort)(r >> 16);
}
__device__ __forceinline__ float bf2f(ushort u) {
  return __uint_as_float(((unsigned)u) << 16);
}

// ---------------- CSR build ----------------
__global__ void zero_int(int* __restrict__ p, int n) {
  int i = blockIdx.x * blockDim.x + threadIdx.x;
  if (i < n) p[i] = 0;
}

__global__ void hist_deg(const int* __restrict__ dst, int* __restrict__ deg, int E) {
  int e = blockIdx.x * blockDim.x + threadIdx.x;
  if (e >= E) return;
  atomicAdd(&deg[dst[e]], 1);
}

// per-block exclusive scan of deg -> rowptr[0..N), block totals -> partial[b]
__global__ __launch_bounds__(SCAN_T) void scan_local(const int* __restrict__ deg,
                                                     int* __restrict__ rowptr,
                                                     int* __restrict__ partial, int N) {
  __shared__ int sdata[SCAN_T];
  int t = threadIdx.x;
  int base = blockIdx.x * SCAN_ELEMS + t * 4;
  int v[4], s = 0;
#pragma unroll
  for (int k = 0; k < 4; ++k) {
    v[k] = (base + k < N) ? deg[base + k] : 0;
    s += v[k];
  }
  sdata[t] = s;
  __syncthreads();
  for (int off = 1; off < SCAN_T; off <<= 1) {
    int add = (t >= off) ? sdata[t - off] : 0;
    __syncthreads();
    sdata[t] += add;
    __syncthreads();
  }
  int run = sdata[t] - s;  // exclusive prefix of this thread's chunk
  if (t == SCAN_T - 1) partial[blockIdx.x] = sdata[t];
#pragma unroll
  for (int k = 0; k < 4; ++k) {
    if (base + k < N) rowptr[base + k] = run;
    run += v[k];
  }
}

// single-block exclusive scan of partial[0..nb), total appended at partial[nb]
__global__ __launch_bounds__(SCAN_T) void scan_partial(int* __restrict__ partial, int nb) {
  __shared__ int sdata[SCAN_T];
  int t = threadIdx.x;
  int v = (t < nb) ? partial[t] : 0;
  sdata[t] = v;
  __syncthreads();
  for (int off = 1; off < SCAN_T; off <<= 1) {
    int add = (t >= off) ? sdata[t - off] : 0;
    __syncthreads();
    sdata[t] += add;
    __syncthreads();
  }
  if (t < nb) partial[t] = sdata[t] - v;
  if (t == nb - 1) partial[nb] = sdata[t];
}

// rowptr[i] += partial[block]; rowptr[N] = total; zero fill for scatter
__global__ void scan_add(int* __restrict__ rowptr, const int* __restrict__ partial,
                         int* __restrict__ fill, int N) {
  int i = blockIdx.x * blockDim.x + threadIdx.x;
  if (i < N) {
    rowptr[i] += partial[i / SCAN_ELEMS];
    fill[i] = 0;
  }
  if (i == N) rowptr[N] = partial[(N + SCAN_ELEMS - 1) / SCAN_ELEMS];
}

__global__ void scatter_edges(const int* __restrict__ src, const int* __restrict__ dst,
                              const int* __restrict__ et, const int* __restrict__ rowptr,
                              int* __restrict__ fill, int* __restrict__ srcpk, int E) {
  int e = blockIdx.x * blockDim.x + threadIdx.x;
  if (e >= E) return;
  int d = dst[e];
  int pos = rowptr[d] + atomicAdd(&fill[d], 1);
  srcpk[pos] = src[e] | (et[e] << 30);
}

// ---------------- weights ----------------
// Packed bf16 W: Wpk[(k>>3)*192 + j][k&7]
__global__ void build_wpk(const float* __restrict__ basis, const float* __restrict__ comp,
                          const float* __restrict__ root, ushort* __restrict__ Wpk, int Kin) {
  int idx = blockIdx.x * blockDim.x + threadIdx.x;
  if (idx >= Kin * NCOL) return;
  int k = idx / NCOL, j = idx - k * NCOL;
  float v;
  if (j < 64) {
    v = root[k * 64 + j];
  } else {
    int r = (j >> 6) - 1, o = j & 63;
    float s = 0.f;
#pragma unroll
    for (int b = 0; b < BB; ++b)
      s = fmaf(comp[r * BB + b], basis[((size_t)b * Kin + k) * 64 + o], s);
    v = s;
  }
  Wpk[(((size_t)(k >> 3) * NCOL + j) << 3) + (k & 7)] = f2bf(v);
}

// ---------------- GEMM (MFMA bf16, split-col waves, BK=64 dbuf LDS) ----------------
template <int K, int BF16IN>
__global__ __launch_bounds__(256, 4) void gemm_mfma(const void* __restrict__ Xv,
                                                    const ushort* __restrict__ Wpk,
                                                    ushort* __restrict__ Y, int N) {
  constexpr int BK  = 64;
  constexpr int NC  = K / BK;
  constexpr int NLD = BF16IN ? (64 * (BK / 8) / 256) : (64 * (BK / 4) / 256);
  __shared__ ushort As[(NC > 1 ? 2 : 1) * 64 * BK];

  const int row0 = blockIdx.x * 64;
  const int tid  = threadIdx.x;
  const int wid  = tid >> 6;
  const int lane = tid & 63;
  const int lrow = lane & 15;
  const int lhi  = lane >> 4;

  const float*  Xf = (const float*)Xv;
  const ushort* Xh = (const ushort*)Xv;

  float4 pf[BF16IN ? 1 : NLD];
  u16x8  pfh[BF16IN ? NLD : 1];

#define LOAD_CHUNK(c)                                                              \
  if constexpr (BF16IN) {                                                          \
    _Pragma("unroll") for (int it = 0; it < NLD; ++it) {                           \
      int idx = tid + it * 256;                                                    \
      int row = idx / (BK / 8), kq = idx - row * (BK / 8);                         \
      int r = row0 + row;                                                          \
      pfh[it] = (u16x8){0, 0, 0, 0, 0, 0, 0, 0};                                   \
      if (r < N) pfh[it] = ((const u16x8*)Xh)[(size_t)r * (K / 8) + (c) * (BK / 8) + kq]; \
    }                                                                              \
  } else {                                                                         \
    _Pragma("unroll") for (int it = 0; it < NLD; ++it) {                           \
      int idx = tid + it * 256;                                                    \
      int row = idx / (BK / 4), kq = idx - row * (BK / 4);                         \
      int r = row0 + row;                                                          \
      pf[it] = make_float4(0.f, 0.f, 0.f, 0.f);                                    \
      if (r < N) pf[it] = ((const float4*)Xf)[(size_t)r * (K / 4) + (c) * (BK / 4) + kq]; \
    }                                                                              \
  }

#define COMMIT_CHUNK(buf)                                                          \
  {                                                                                \
    char* Aw = (char*)As + (size_t)(buf) * 64 * BK * 2;                            \
    if constexpr (BF16IN) {                                                        \
      _Pragma("unroll") for (int it = 0; it < NLD; ++it) {                         \
        int idx = tid + it * 256;                                                  \
        int row = idx / (BK / 8), kq = idx - row * (BK / 8);                       \
        int byte = ((row * BK + kq * 8) * 2) ^ ((row & 7) << 4);                   \
        *(u16x8*)(Aw + byte) = pfh[it];                                            \
      }                                                                            \
    } else {                                                                       \
      _Pragma("unroll") for (int it = 0; it < NLD; ++it) {                         \
        int idx = tid + it * 256;                                                  \
        int row = idx / (BK / 4), kq = idx - row * (BK / 4);                       \
        ushort4 b;                                                                 \
        b.x = f2bf(pf[it].x); b.y = f2bf(pf[it].y);                                \
        b.z = f2bf(pf[it].z); b.w = f2bf(pf[it].w);                                \
        int byte = ((row * BK + kq * 4) * 2) ^ ((row & 7) << 4);                   \
        *(ushort4*)(Aw + byte) = b;                                                \
      }                                                                            \
    }                                                                              \
  }

  // prologue: chunk 0
  LOAD_CHUNK(0)
  COMMIT_CHUNK(0)
  __syncthreads();

  f32x4 acc[4][3];
#pragma unroll
  for (int s = 0; s < 4; ++s)
#pragma unroll
    for (int c = 0; c < 3; ++c) acc[s][c] = (f32x4){0.f, 0.f, 0.f, 0.f};

  for (int c = 0; c < NC; ++c) {
    if (c + 1 < NC) { LOAD_CHUNK(c + 1) }   // overlaps MFMA below
    const char* Ab = (const char*)As + (size_t)(NC > 1 ? (c & 1) : 0) * 64 * BK * 2;
#pragma unroll
    for (int t = 0; t < BK / 32; ++t) {
      int g = (c * (BK / 32) + t) * 4 + lhi;  // bf16x8 k-group index
      const bf16x8* bp = (const bf16x8*)Wpk + (size_t)g * NCOL + wid * 48 + lrow;
      bf16x8 b0 = bp[0];
      bf16x8 b1 = bp[16];
      bf16x8 b2 = bp[32];
      bf16x8 a[4];
#pragma unroll
      for (int s = 0; s < 4; ++s) {
        int arow = s * 16 + lrow;
        int abyte = ((arow * BK + t * 32 + lhi * 8) * 2) ^ ((arow & 7) << 4);
        a[s] = *(const bf16x8*)(Ab + abyte);
      }
#pragma unroll
      for (int s = 0; s < 4; ++s) {
        acc[s][0] = __builtin_amdgcn_mfma_f32_16x16x32_bf16(a[s], b0, acc[s][0], 0, 0, 0);
        acc[s][1] = __builtin_amdgcn_mfma_f32_16x16x32_bf16(a[s], b1, acc[s][1], 0, 0, 0);
        acc[s][2] = __builtin_amdgcn_mfma_f32_16x16x32_bf16(a[s], b2, acc[s][2], 0, 0, 0);
      }
    }
    if (c + 1 < NC) {
      __syncthreads();
      COMMIT_CHUNK((c + 1) & 1)
      __syncthreads();
    }
  }
#undef LOAD_CHUNK
#undef COMMIT_CHUNK

  // C/D: col = lane&15, row = (lane>>4)*4 + reg   [m89]
#pragma unroll
  for (int s = 0; s < 4; ++s) {
#pragma unroll
    for (int cc = 0; cc < 3; ++cc) {
#pragma unroll
      for (int j = 0; j < 4; ++j) {
        int r = row0 + s * 16 + lhi * 4 + j;
        if (r < N) Y[(size_t)r * NCOL + wid * 48 + cc * 16 + lrow] = f2bf(acc[s][cc][j]);
      }
    }
  }
}

// ---------------- fused per-node aggregation (8 edges per gather instr) ----------------
// Wave per node. 8 groups x 8 lanes; group g handles edge slot g of a batch,
// lane (l&7) holds features [(l&7)*8, +8) as u16x8 (16B). 2 batches in flight.
// Reduce across groups via shfl_xor(8,16,32). res = root + bias + mean0 + mean1.
template <int RELU, int GATH>
__global__ __launch_bounds__(256) void fused_agg(const ushort* __restrict__ Y,
                                                 const int* __restrict__ rowptr,
                                                 const int* __restrict__ srcpk,
                                                 const float* __restrict__ bias,
                                                 const float* __restrict__ gw,
                                                 ushort* __restrict__ accout,
                                                 float* __restrict__ hval, int N) {
  int n = blockIdx.x * 4 + (threadIdx.x >> 6);
  if (n >= N) return;
  const int lane = threadIdx.x & 63;
  const int g    = lane >> 3;        // edge slot 0..7
  const int f0   = (lane & 7) * 8;   // feature slice

  float a0[8], a1[8];
#pragma unroll
  for (int j = 0; j < 8; ++j) { a0[j] = 0.f; a1[j] = 0.f; }
  float c0 = 0.f, c1 = 0.f;

  const int beg = rowptr[n], end = rowptr[n + 1];
  for (int i = beg; i < end; i += 16) {
    int eA = i + g, eB = i + 8 + g;
    bool vA = eA < end, vB = eB < end;
    int pkA = 0, pkB = 0;
    if (vA) pkA = srcpk[eA];
    if (vB) pkB = srcpk[eB];
    u16x8 xA = (u16x8){0, 0, 0, 0, 0, 0, 0, 0}, xB = xA;
    if (vA) xA = *(const u16x8*)(Y + (size_t)(pkA & 0x3fffffff) * NCOL + 64 +
                                 ((pkA >> 30) << 6) + f0);
    if (vB) xB = *(const u16x8*)(Y + (size_t)(pkB & 0x3fffffff) * NCOL + 64 +
                                 ((pkB >> 30) << 6) + f0);
    float rA = (vA && (pkA >> 30)) ? 1.f : 0.f;
    float sA = vA ? 1.f : 0.f;
    float rB = (vB && (pkB >> 30)) ? 1.f : 0.f;
    float sB = vB ? 1.f : 0.f;
    c0 += (sA - rA) + (sB - rB);
    c1 += rA + rB;
#pragma unroll
    for (int j = 0; j < 8; ++j) {
      float fA = bf2f(xA[j]), fB = bf2f(xB[j]);
      a0[j] += (sA - rA) * fA + (sB - rB) * fB;
      a1[j] += rA * fA + rB * fB;
    }
  }

  // fold the 8 edge-groups
#pragma unroll
  for (int msk = 8; msk <= 32; msk <<= 1) {
#pragma unroll
    for (int j = 0; j < 8; ++j) {
      a0[j] += __shfl_xor(a0[j], msk);
      a1[j] += __shfl_xor(a1[j], msk);
    }
    c0 += __shfl_xor(c0, msk);
    c1 += __shfl_xor(c1, msk);
  }

  float inv0 = 1.f / fmaxf(c0, 1.f);
  float inv1 = 1.f / fmaxf(c1, 1.f);
  u16x8 rv = *(const u16x8*)(Y + (size_t)n * NCOL + f0);
  float4 bA = *(const float4*)(bias + f0);
  float4 bB = *(const float4*)(bias + f0 + 4);
  float bb[8] = {bA.x, bA.y, bA.z, bA.w, bB.x, bB.y, bB.z, bB.w};
  float res[8];
#pragma unroll
  for (int j = 0; j < 8; ++j) {
    float v = bf2f(rv[j]) + bb[j] + a0[j] * inv0 + a1[j] * inv1;
    res[j] = RELU ? fmaxf(v, 0.f) : v;
  }
  if (accout && g == 0) {
    u16x8 o;
#pragma unroll
    for (int j = 0; j < 8; ++j) o[j] = f2bf(res[j]);
    *(u16x8*)(accout + (size_t)n * 64 + f0) = o;
  }
  if (GATH) {
    float4 gA = *(const float4*)(gw + f0);
    float4 gB = *(const float4*)(gw + f0 + 4);
    float gg[8] = {gA.x, gA.y, gA.z, gA.w, gB.x, gB.y, gB.z, gB.w};
    float dot = 0.f;
#pragma unroll
    for (int j = 0; j < 8; ++j) dot = fmaf(res[j], gg[j], dot);
    dot += __shfl_xor(dot, 1);
    dot += __shfl_xor(dot, 2);
    dot += __shfl_xor(dot, 4);
    if (lane == 0) hval[n] = dot;
  }
}

// ---------------- GAT (CSR, wave per node, lane per edge) ----------------
__device__ __forceinline__ float leaky(float x) { return x > 0.f ? x : 0.2f * x; }

__global__ __launch_bounds__(256) void gat_csr(const int* __restrict__ rowptr,
                                               const int* __restrict__ srcpk,
                                               const float* __restrict__ hval,
                                               const float* __restrict__ as_,
                                               const float* __restrict__ ad_,
                                               const float* __restrict__ gb,
                                               float* __restrict__ out, int N) {
  int n = blockIdx.x * 4 + (threadIdx.x >> 6);
  if (n >= N) return;
  const int lane = threadIdx.x & 63;
  float as = *as_, ad = *ad_;
  float hv = hval[n];
  float adn = hv * ad;
  float eself = leaky(hv * as + adn);
  int beg = rowptr[n], end = rowptr[n + 1];
  int deg = end - beg;
  float m, den, acc;
  if (deg <= 64) {  // single pass, everything in registers
    bool valid = lane < deg;
    float hs = 0.f;
    if (valid) hs = hval[srcpk[beg + lane] & 0x3fffffff];
    float e = valid ? leaky(hs * as + adn) : -3.4e38f;
    m = fmaxf(e, eself);
#pragma unroll
    for (int o = 32; o > 0; o >>= 1) m = fmaxf(m, __shfl_xor(m, o));
    float ex = valid ? expf(e - m) : 0.f;
    den = ex;
    acc = ex * hs;
#pragma unroll
    for (int o = 32; o > 0; o >>= 1) {
      den += __shfl_xor(den, o);
      acc += __shfl_xor(acc, o);
    }
  } else {  // rare: strided two-pass
    m = eself;
    for (int i = beg + lane; i < end; i += 64)
      m = fmaxf(m, leaky(hval[srcpk[i] & 0x3fffffff] * as + adn));
#pragma unroll
    for (int o = 32; o > 0; o >>= 1) m = fmaxf(m, __shfl_xor(m, o));
    float dl = 0.f, al = 0.f;
    for (int i = beg + lane; i < end; i += 64) {
      float hs = hval[srcpk[i] & 0x3fffffff];
      float ex = expf(leaky(hs * as + adn) - m);
      dl += ex;
      al += ex * hs;
    }
    den = dl;
    acc = al;
#pragma unroll
    for (int o = 32; o > 0; o >>= 1) {
      den += __shfl_xor(den, o);
      acc += __shfl_xor(acc, o);
    }
  }
  float es = expf(eself - m);
  den += es;
  acc += es * hv;
  if (lane == 0) out[n] = acc / den + *gb;
}

// ---------------- launch ----------------
extern "C" void kernel_launch(void* const* d_in, const int* in_sizes, int n_in,
                              void* d_out, int out_size, void* d_ws, size_t ws_size,
                              hipStream_t stream) {
  const float* x      = (const float*)d_in[0];
  const int*   eidx   = (const int*)d_in[1];
  const int*   etype  = (const int*)d_in[2];
  const float* basis1 = (const float*)d_in[3];
  const float* comp1  = (const float*)d_in[4];
  const float* root1  = (const float*)d_in[5];
  const float* bias1  = (const float*)d_in[6];
  const float* basis2 = (const float*)d_in[7];
  const float* comp2  = (const float*)d_in[8];
  const float* root2  = (const float*)d_in[9];
  const float* bias2  = (const float*)d_in[10];
  const float* gat_w  = (const float*)d_in[11];
  const float* att_s  = (const float*)d_in[12];
  const float* att_d  = (const float*)d_in[13];
  const float* gat_b  = (const float*)d_in[14];

  const int N = in_sizes[0] / 512;   // 100000
  const int E = in_sizes[1] / 2;     // 1600000
  const int* src = eidx;
  const int* dst = eidx + E;

  // workspace carve-up (16B-aligned segments)
  char* p = (char*)d_ws;
  ushort* Y    = (ushort*)p; p += (size_t)N * NCOL * 2;        // 38.4 MB (bf16)
  ushort* acc1 = (ushort*)p; p += (size_t)N * 64 * 2;          // 12.8 MB (bf16)
  ushort* Wpk  = (ushort*)p; p += (size_t)512 * NCOL * 2;      // 0.2 MB
  float* hval  = (float*)p;  p += (size_t)N * 4;
  int* deg     = (int*)p;    p += (size_t)N * 4;               // reused as fill
  int* rowptr  = (int*)p;    p += (size_t)(N + 16) * 4;
  int* partial = (int*)p;    p += (size_t)(SCAN_T + 16) * 4;
  int* srcpk   = (int*)p;    p += (size_t)E * 4;               // 6.4 MB
  float* out   = (float*)d_out;
  int* fill    = deg;

  const int TB = 256;
  const int GB = (N + 63) / 64;
  const int nb = (N + SCAN_ELEMS - 1) / SCAN_ELEMS;

  // ---- CSR build (shared by both layers and GAT) ----
  zero_int<<<(N + TB - 1) / TB, TB, 0, stream>>>(deg, N);
  hist_deg<<<(E + TB - 1) / TB, TB, 0, stream>>>(dst, deg, E);
  scan_local<<<nb, SCAN_T, 0, stream>>>(deg, rowptr, partial, N);
  scan_partial<<<1, SCAN_T, 0, stream>>>(partial, nb);
  scan_add<<<(N + 1 + TB - 1) / TB, TB, 0, stream>>>(rowptr, partial, fill, N);
  scatter_edges<<<(E + TB - 1) / TB, TB, 0, stream>>>(src, dst, etype, rowptr, fill, srcpk, E);

  // ---- layer 1 (K=512, f32 input) ----
  build_wpk<<<(512 * NCOL + TB - 1) / TB, TB, 0, stream>>>(basis1, comp1, root1, Wpk, 512);
  gemm_mfma<512, 0><<<GB, 256, 0, stream>>>(x, Wpk, Y, N);
  fused_agg<1, 0><<<(N + 3) / 4, TB, 0, stream>>>(Y, rowptr, srcpk, bias1, nullptr, acc1,
                                                  nullptr, N);

  // ---- layer 2 (K=64, bf16 input) ----
  build_wpk<<<(64 * NCOL + TB - 1) / TB, TB, 0, stream>>>(basis2, comp2, root2, Wpk, 64);
  gemm_mfma<64, 1><<<GB, 256, 0, stream>>>(acc1, Wpk, Y, N);
  fused_agg<0, 1><<<(N + 3) / 4, TB, 0, stream>>>(Y, rowptr, srcpk, bias2, gat_w, nullptr,
                                                  hval, N);

  // ---- GAT ----
  gat_csr<<<(N + 3) / 4, TB, 0, stream>>>(rowptr, srcpk, hval, att_s, att_d, gat_b,
                                          out, N);
}